// Round 13
// baseline (277.648 us; speedup 1.0000x reference)
//
#include <hip/hip_runtime.h>

#define NNODES  100000
#define NEDGES  3200000
#define NGRAPHS 2000
#define INDIM   12
#define HID     48
#define CEPS    1e-5f
#define CAP     96      // padded per-node slot capacity

#define BSHIFT   8
#define NBUCKET  ((NNODES + 255) / 256)     // 391 buckets of 256 nodes
#define CAPB     8704
#define P1_BLOCKS 250
#define P1_THREADS 1024
#define P1_EDGES (NEDGES / P1_BLOCKS)       // 12800 edges per block
#define GSHIFT   15                         // 4 src groups of 32768 nodes (3.1MB bf16 h0 each)

#define SCAN_CHUNK 1024
#define NSCAN_BLOCKS ((NNODES + SCAN_CHUNK - 1) / SCAN_CHUNK)

__device__ inline void f4add(float4& a, const float4 b) {
  a.x += b.x; a.y += b.y; a.z += b.z; a.w += b.w;
}
__device__ inline float blo(unsigned u) { return __uint_as_float(u << 16); }
__device__ inline float bhi(unsigned u) { return __uint_as_float(u & 0xffff0000u); }
__device__ inline unsigned bpack(float a, float b) {
  unsigned ua = __float_as_uint(a), ub = __float_as_uint(b);
  ua = (ua + 0x7fffu + ((ua >> 16) & 1u)) >> 16;
  ub = (ub + 0x7fffu + ((ub >> 16) & 1u)) >> 16;
  return ua | (ub << 16);
}

// ==================================================================
// x -> bf16 copy
// ==================================================================
__global__ __launch_bounds__(256) void convert_x_kernel(
    const float* __restrict__ x, uint4* __restrict__ xb) {
  int idx = blockIdx.x * blockDim.x + threadIdx.x;
  if (idx >= NNODES * INDIM / 8) return;
  const float4* p = (const float4*)(x + (size_t)idx * 8);
  float4 v0 = p[0], v1 = p[1];
  uint4 o;
  o.x = bpack(v0.x, v0.y); o.y = bpack(v0.z, v0.w);
  o.z = bpack(v1.x, v1.y); o.w = bpack(v1.z, v1.w);
  xb[idx] = o;
}

// ==================================================================
// phase 1: bucket edges by dst>>8 (packed (dstlocal<<24)|src)
// 1024 threads/block (16 waves); 250 blocks keep per-bucket write
// runs >= ~33 edges to limit sector write amplification.
// ==================================================================
__global__ __launch_bounds__(P1_THREADS) void bucket_p1_kernel(
    const int* __restrict__ ei, int* __restrict__ bucket_cursor,
    unsigned int* __restrict__ bucketed) {
  __shared__ int hist[NBUCKET];
  __shared__ int lcur[NBUCKET];
  for (int b = threadIdx.x; b < NBUCKET; b += P1_THREADS) hist[b] = 0;
  __syncthreads();
  const int base = blockIdx.x * P1_EDGES;
  for (int off = threadIdx.x * 4; off < P1_EDGES; off += P1_THREADS * 4) {
    int4 d4 = *(const int4*)(ei + NEDGES + base + off);
    atomicAdd(&hist[(d4.x >> BSHIFT) % NBUCKET], 1);
    atomicAdd(&hist[(d4.y >> BSHIFT) % NBUCKET], 1);
    atomicAdd(&hist[(d4.z >> BSHIFT) % NBUCKET], 1);
    atomicAdd(&hist[(d4.w >> BSHIFT) % NBUCKET], 1);
  }
  __syncthreads();
  for (int b = threadIdx.x; b < NBUCKET; b += P1_THREADS)
    lcur[b] = (hist[b] > 0) ? atomicAdd(&bucket_cursor[b], hist[b]) : 0;
  __syncthreads();
  for (int off = threadIdx.x * 4; off < P1_EDGES; off += P1_THREADS * 4) {
    int4 s4 = *(const int4*)(ei + base + off);
    int4 d4 = *(const int4*)(ei + NEDGES + base + off);
    {
      int b0 = (d4.x >> BSHIFT) % NBUCKET; int p = atomicAdd(&lcur[b0], 1);
      if ((unsigned)p < (unsigned)CAPB)
        bucketed[(size_t)b0 * CAPB + p] = ((unsigned)(d4.x & 255) << 24) | ((unsigned)s4.x & 0xFFFFFFu);
    }
    {
      int b1 = (d4.y >> BSHIFT) % NBUCKET; int p = atomicAdd(&lcur[b1], 1);
      if ((unsigned)p < (unsigned)CAPB)
        bucketed[(size_t)b1 * CAPB + p] = ((unsigned)(d4.y & 255) << 24) | ((unsigned)s4.y & 0xFFFFFFu);
    }
    {
      int b2 = (d4.z >> BSHIFT) % NBUCKET; int p = atomicAdd(&lcur[b2], 1);
      if ((unsigned)p < (unsigned)CAPB)
        bucketed[(size_t)b2 * CAPB + p] = ((unsigned)(d4.z & 255) << 24) | ((unsigned)s4.z & 0xFFFFFFu);
    }
    {
      int b3 = (d4.w >> BSHIFT) % NBUCKET; int p = atomicAdd(&lcur[b3], 1);
      if ((unsigned)p < (unsigned)CAPB)
        bucketed[(size_t)b3 * CAPB + p] = ((unsigned)(d4.w & 255) << 24) | ((unsigned)s4.w & 0xFFFFFFu);
    }
  }
}

// ==================================================================
// phase 2: one block per bucket; 4-group counting sort by src>>15.
// slots[node] sorted by group; cnt = total | b1<<8 | b2<<16 | b3<<24
// (bases/total all <= CAP=96, fit 8 bits).
// ==================================================================
__global__ __launch_bounds__(256) void fill_p2_kernel(
    const unsigned int* __restrict__ bucketed, const int* __restrict__ bucket_cursor,
    int* __restrict__ slots, int* __restrict__ cnt) {
  __shared__ int cbase[256][4];
  __shared__ int ccur[256][4];
#pragma unroll
  for (int g = 0; g < 4; g++) { cbase[threadIdx.x][g] = 0; ccur[threadIdx.x][g] = 0; }
  __syncthreads();
  int b = blockIdx.x;
  int count = bucket_cursor[b];
  if (count > CAPB) count = CAPB;
  size_t bb = (size_t)b * CAPB;
  // pass 1: counts per (dstlocal, group)
  for (int i = threadIdx.x; i < count; i += 256) {
    unsigned v = bucketed[bb + i];
    int dl = (int)(v >> 24);
    int g = (int)((v & 0xFFFFFFu) >> GSHIFT);   // 0..3
    atomicAdd(&cbase[dl][g], 1);
  }
  __syncthreads();
  // per-node exclusive bases (thread dl owns its row), clamped at CAP
  {
    int dl = threadIdx.x;
    int c0 = cbase[dl][0], c1 = cbase[dl][1], c2 = cbase[dl][2], c3 = cbase[dl][3];
    int b1 = min(c0, CAP);
    int b2 = min(c0 + c1, CAP);
    int b3 = min(c0 + c1 + c2, CAP);
    int tot = min(c0 + c1 + c2 + c3, CAP);
    cbase[dl][0] = 0; cbase[dl][1] = b1; cbase[dl][2] = b2; cbase[dl][3] = b3;
    int node = b * 256 + dl;
    if (node < NNODES) cnt[node] = tot | (b1 << 8) | (b2 << 16) | (b3 << 24);
  }
  __syncthreads();
  // pass 2: scatter sorted by group
  for (int i = threadIdx.x; i < count; i += 256) {
    unsigned v = bucketed[bb + i];
    int dl = (int)(v >> 24);
    int s = (int)(v & 0xFFFFFFu);
    int g = s >> GSHIFT;
    int node = b * 256 + dl;
    if (node < NNODES) {
      int p = cbase[dl][g] + atomicAdd(&ccur[dl][g], 1);
      if (p < CAP) slots[(size_t)node * CAP + p] = s;
    }
  }
}

// ==================================================================
// graph segment starts
// ==================================================================
__global__ __launch_bounds__(64) void graph_start_kernel(
    const int* __restrict__ batch, int* __restrict__ gstart) {
  int g = blockIdx.x * blockDim.x + threadIdx.x;
  if (g > NGRAPHS) return;
  int lo = 0, hi = NNODES;
  while (lo < hi) {
    int mid = (lo + hi) >> 1;
    if (batch[mid] < g) lo = mid + 1; else hi = mid;
  }
  gstart[g] = lo;
}

// ==================================================================
// agg0: bf16 gather, 3 lanes/node. xb is 2.4MB (L2-fit) -> single loop.
// ==================================================================
#define GATH24(BEGIN, COUNT)                                              \
  {                                                                       \
    int n = 0;                                                            \
    for (; n + 4 <= (COUNT); n += 4) {                                    \
      int sa = slots[(BEGIN) + n + 0];                                    \
      int sb = slots[(BEGIN) + n + 1];                                    \
      int sc = slots[(BEGIN) + n + 2];                                    \
      int sd = slots[(BEGIN) + n + 3];                                    \
      uint2 ua = xb[(size_t)sa * 3 + q];                                  \
      uint2 ub = xb[(size_t)sb * 3 + q];                                  \
      uint2 uc = xb[(size_t)sc * 3 + q];                                  \
      uint2 ud = xb[(size_t)sd * 3 + q];                                  \
      a0[0] += blo(ua.x); a0[1] += bhi(ua.x); a0[2] += blo(ua.y); a0[3] += bhi(ua.y); \
      a1[0] += blo(ub.x); a1[1] += bhi(ub.x); a1[2] += blo(ub.y); a1[3] += bhi(ub.y); \
      a2[0] += blo(uc.x); a2[1] += bhi(uc.x); a2[2] += blo(uc.y); a2[3] += bhi(uc.y); \
      a3[0] += blo(ud.x); a3[1] += bhi(ud.x); a3[2] += blo(ud.y); a3[3] += bhi(ud.y); \
    }                                                                     \
    for (; n < (COUNT); n++) {                                            \
      uint2 u = xb[(size_t)slots[(BEGIN) + n] * 3 + q];                   \
      a0[0] += blo(u.x); a0[1] += bhi(u.x); a0[2] += blo(u.y); a0[3] += bhi(u.y); \
    }                                                                     \
  }

__global__ __launch_bounds__(256) void agg0_b_kernel(
    const uint2* __restrict__ xb, const int* __restrict__ slots,
    const int* __restrict__ cnt, float* __restrict__ agg) {
  int tid = blockIdx.x * blockDim.x + threadIdx.x;
  int node = tid / 3;
  int q = tid - node * 3;
  if (node >= NNODES) return;
  size_t start = (size_t)node * CAP;
  int tot = cnt[node] & 0xFF;
  float a0[4] = {0,0,0,0}, a1[4] = {0,0,0,0}, a2[4] = {0,0,0,0}, a3[4] = {0,0,0,0};
  GATH24(start, tot);
  float inv = 1.0f / fmaxf((float)tot, 1.0f);
  float4 r;
  r.x = (a0[0] + a1[0] + a2[0] + a3[0]) * inv;
  r.y = (a0[1] + a1[1] + a2[1] + a3[1]) * inv;
  r.z = (a0[2] + a1[2] + a2[2] + a3[2]) * inv;
  r.w = (a0[3] + a1[3] + a2[3] + a3[3]) * inv;
  *(float4*)(agg + (size_t)node * INDIM + q * 4) = r;
}

// ==================================================================
// sage0 (k-quarter split) + stats via lane butterfly
// ==================================================================
__global__ __launch_bounds__(256) void sage0_4k_kernel(
    const float* __restrict__ x, const float* __restrict__ agg,
    const float* __restrict__ wl, const float* __restrict__ wr,
    const float* __restrict__ bc, float* __restrict__ hpre,
    float* __restrict__ stats) {
  __shared__ float swl[HID * INDIM], swr[HID * INDIM], sbc[HID];
  __shared__ float ssum[HID], ssq[HID];
  for (int t = threadIdx.x; t < HID * INDIM; t += 256) { swl[t] = wl[t]; swr[t] = wr[t]; }
  if (threadIdx.x < HID) {
    sbc[threadIdx.x] = bc[threadIdx.x];
    ssum[threadIdx.x] = 0.f; ssq[threadIdx.x] = 0.f;
  }
  __syncthreads();
  int tid = blockIdx.x * 256 + threadIdx.x;
  int node = tid >> 2;
  int kq = tid & 3;
  bool valid = (node < NNODES);
  float s[12], sq[12];
  if (valid) {
    float xi[INDIM], ag[INDIM];
    const float4* xp = (const float4*)(x + (size_t)node * INDIM);
    const float4* mp = (const float4*)(agg + (size_t)node * INDIM);
#pragma unroll
    for (int q = 0; q < 3; q++) {
      float4 v = xp[q];
      xi[q * 4 + 0] = v.x; xi[q * 4 + 1] = v.y; xi[q * 4 + 2] = v.z; xi[q * 4 + 3] = v.w;
      float4 m = mp[q];
      ag[q * 4 + 0] = m.x; ag[q * 4 + 1] = m.y; ag[q * 4 + 2] = m.z; ag[q * 4 + 3] = m.w;
    }
    float o[12];
#pragma unroll
    for (int t = 0; t < 12; t++) {
      int k = kq * 12 + t;
      const float* wlr = swl + k * INDIM;
      const float* wrr = swr + k * INDIM;
      float acc = sbc[k];
#pragma unroll
      for (int j = 0; j < INDIM; j++) acc += ag[j] * wlr[j] + xi[j] * wrr[j];
      o[t] = acc;
    }
    float* dst = hpre + (size_t)node * HID + kq * 12;
    *(float4*)(dst + 0) = make_float4(o[0], o[1], o[2], o[3]);
    *(float4*)(dst + 4) = make_float4(o[4], o[5], o[6], o[7]);
    *(float4*)(dst + 8) = make_float4(o[8], o[9], o[10], o[11]);
#pragma unroll
    for (int t = 0; t < 12; t++) { s[t] = o[t]; sq[t] = o[t] * o[t]; }
  } else {
#pragma unroll
    for (int t = 0; t < 12; t++) { s[t] = 0.f; sq[t] = 0.f; }
  }
#pragma unroll
  for (int off = 4; off <= 32; off <<= 1) {
#pragma unroll
    for (int t = 0; t < 12; t++) {
      s[t] += __shfl_xor(s[t], off);
      sq[t] += __shfl_xor(sq[t], off);
    }
  }
  int lane = threadIdx.x & 63;
  if (lane < 4) {
#pragma unroll
    for (int t = 0; t < 12; t++) {
      atomicAdd(&ssum[lane * 12 + t], s[t]);
      atomicAdd(&ssq[lane * 12 + t], sq[t]);
    }
  }
  __syncthreads();
  if (threadIdx.x < 2 * HID)
    atomicAdd(&stats[threadIdx.x],
              threadIdx.x < HID ? ssum[threadIdx.x] : ssq[threadIdx.x - HID]);
}

// ==================================================================
// BN+ReLU -> bf16
// ==================================================================
__global__ __launch_bounds__(256) void bn_relu_b16_kernel(
    const float* __restrict__ hpre, const float* __restrict__ stats,
    const float* __restrict__ g, const float* __restrict__ be,
    uint4* __restrict__ h0b) {
  __shared__ float sc[HID], sh[HID];
  if (threadIdx.x < HID) {
    int k = threadIdx.x;
    float m = stats[k] * (1.0f / NNODES);
    float v = stats[HID + k] * (1.0f / NNODES) - m * m;
    float s = g[k] * rsqrtf(v + CEPS);
    sc[k] = s; sh[k] = be[k] - m * s;
  }
  __syncthreads();
  int idx = blockIdx.x * 256 + threadIdx.x;
  if (idx >= NNODES * 6) return;
  const float4* p = (const float4*)(hpre + (size_t)idx * 8);
  float4 v0 = p[0], v1 = p[1];
  int kb = (idx % 6) * 8;
  float r0 = fmaxf(v0.x * sc[kb + 0] + sh[kb + 0], 0.f);
  float r1 = fmaxf(v0.y * sc[kb + 1] + sh[kb + 1], 0.f);
  float r2 = fmaxf(v0.z * sc[kb + 2] + sh[kb + 2], 0.f);
  float r3 = fmaxf(v0.w * sc[kb + 3] + sh[kb + 3], 0.f);
  float r4 = fmaxf(v1.x * sc[kb + 4] + sh[kb + 4], 0.f);
  float r5 = fmaxf(v1.y * sc[kb + 5] + sh[kb + 5], 0.f);
  float r6 = fmaxf(v1.z * sc[kb + 6] + sh[kb + 6], 0.f);
  float r7 = fmaxf(v1.w * sc[kb + 7] + sh[kb + 7], 0.f);
  uint4 o;
  o.x = bpack(r0, r1); o.y = bpack(r2, r3); o.z = bpack(r4, r5); o.w = bpack(r6, r7);
  h0b[idx] = o;
}

// ==================================================================
// agg1: bf16 gather, 6 lanes/node, FOUR src-group segment sweeps
// (each segment's h0b slice ~3.1MB < 4MB XCD-L2)
// ==================================================================
#define GATH48(BEGIN, COUNT)                                              \
  {                                                                       \
    int n = 0;                                                            \
    for (; n + 4 <= (COUNT); n += 4) {                                    \
      int sa = slots[(BEGIN) + n + 0];                                    \
      int sb = slots[(BEGIN) + n + 1];                                    \
      int sc = slots[(BEGIN) + n + 2];                                    \
      int sd = slots[(BEGIN) + n + 3];                                    \
      uint4 ua = h0b[(size_t)sa * 6 + q];                                 \
      uint4 ub = h0b[(size_t)sb * 6 + q];                                 \
      uint4 uc = h0b[(size_t)sc * 6 + q];                                 \
      uint4 ud = h0b[(size_t)sd * 6 + q];                                 \
      a0[0] += blo(ua.x); a0[1] += bhi(ua.x); a0[2] += blo(ua.y); a0[3] += bhi(ua.y); \
      a0[4] += blo(ua.z); a0[5] += bhi(ua.z); a0[6] += blo(ua.w); a0[7] += bhi(ua.w); \
      a1[0] += blo(ub.x); a1[1] += bhi(ub.x); a1[2] += blo(ub.y); a1[3] += bhi(ub.y); \
      a1[4] += blo(ub.z); a1[5] += bhi(ub.z); a1[6] += blo(ub.w); a1[7] += bhi(ub.w); \
      a2[0] += blo(uc.x); a2[1] += bhi(uc.x); a2[2] += blo(uc.y); a2[3] += bhi(uc.y); \
      a2[4] += blo(uc.z); a2[5] += bhi(uc.z); a2[6] += blo(uc.w); a2[7] += bhi(uc.w); \
      a3[0] += blo(ud.x); a3[1] += bhi(ud.x); a3[2] += blo(ud.y); a3[3] += bhi(ud.y); \
      a3[4] += blo(ud.z); a3[5] += bhi(ud.z); a3[6] += blo(ud.w); a3[7] += bhi(ud.w); \
    }                                                                     \
    for (; n < (COUNT); n++) {                                            \
      uint4 u = h0b[(size_t)slots[(BEGIN) + n] * 6 + q];                  \
      a0[0] += blo(u.x); a0[1] += bhi(u.x); a0[2] += blo(u.y); a0[3] += bhi(u.y); \
      a0[4] += blo(u.z); a0[5] += bhi(u.z); a0[6] += blo(u.w); a0[7] += bhi(u.w); \
    }                                                                     \
  }

__global__ __launch_bounds__(256) void agg1_b_kernel(
    const uint4* __restrict__ h0b, const int* __restrict__ slots,
    const int* __restrict__ cnt, float* __restrict__ agg) {
  int tid = blockIdx.x * blockDim.x + threadIdx.x;
  int node = tid / 6;
  int q = tid - node * 6;
  if (node >= NNODES) return;
  size_t start = (size_t)node * CAP;
  int packed = cnt[node];
  int tot = packed & 0xFF;
  int b1 = (packed >> 8) & 0xFF;
  int b2 = (packed >> 16) & 0xFF;
  int b3 = (packed >> 24) & 0xFF;
  float a0[8] = {0,0,0,0,0,0,0,0}, a1[8] = {0,0,0,0,0,0,0,0};
  float a2[8] = {0,0,0,0,0,0,0,0}, a3[8] = {0,0,0,0,0,0,0,0};
  GATH48(start, b1);
  GATH48(start + b1, b2 - b1);
  GATH48(start + b2, b3 - b2);
  GATH48(start + b3, tot - b3);
  float inv = 1.0f / fmaxf((float)tot, 1.0f);
  float* dst = agg + (size_t)node * HID + q * 8;
  float4 r0, r1;
  r0.x = (a0[0] + a1[0] + a2[0] + a3[0]) * inv;
  r0.y = (a0[1] + a1[1] + a2[1] + a3[1]) * inv;
  r0.z = (a0[2] + a1[2] + a2[2] + a3[2]) * inv;
  r0.w = (a0[3] + a1[3] + a2[3] + a3[3]) * inv;
  r1.x = (a0[4] + a1[4] + a2[4] + a3[4]) * inv;
  r1.y = (a0[5] + a1[5] + a2[5] + a3[5]) * inv;
  r1.z = (a0[6] + a1[6] + a2[6] + a3[6]) * inv;
  r1.w = (a0[7] + a1[7] + a2[7] + a3[7]) * inv;
  *(float4*)(dst + 0) = r0;
  *(float4*)(dst + 4) = r1;
}

// ==================================================================
// sage1 (2 nodes/thread, j-quarter split, shfl reduce) + butterfly stats
// ==================================================================
__global__ __launch_bounds__(256) void sage1_2n_kernel(
    const float* __restrict__ agg, const uint2* __restrict__ h0b,
    const float* __restrict__ wl, const float* __restrict__ wr,
    const float* __restrict__ bc, float* __restrict__ hout,
    float* __restrict__ stats) {
  __shared__ float swl[HID * HID], swr[HID * HID], sbc[HID];
  __shared__ float ssum[HID], ssq[HID];
  for (int t = threadIdx.x; t < HID * HID; t += 256) { swl[t] = wl[t]; swr[t] = wr[t]; }
  if (threadIdx.x < HID) {
    sbc[threadIdx.x] = bc[threadIdx.x];
    ssum[threadIdx.x] = 0.f; ssq[threadIdx.x] = 0.f;
  }
  __syncthreads();
  int tid = blockIdx.x * 256 + threadIdx.x;
  int p = tid >> 2;
  int jq = tid & 3;
  bool valid = (p < NNODES / 2);
  const int jb = jq * 12;
  float s[12], sq[12];
  if (valid) {
    int node0 = 2 * p, node1 = 2 * p + 1;
    float a0[12], a1[12], h0v[12], h1v[12];
    const float4* ap0 = (const float4*)(agg + (size_t)node0 * HID + jb);
    const float4* ap1 = (const float4*)(agg + (size_t)node1 * HID + jb);
#pragma unroll
    for (int q = 0; q < 3; q++) {
      float4 v = ap0[q];
      a0[q * 4 + 0] = v.x; a0[q * 4 + 1] = v.y; a0[q * 4 + 2] = v.z; a0[q * 4 + 3] = v.w;
      float4 w = ap1[q];
      a1[q * 4 + 0] = w.x; a1[q * 4 + 1] = w.y; a1[q * 4 + 2] = w.z; a1[q * 4 + 3] = w.w;
    }
    const uint2* hp0 = h0b + (size_t)node0 * 12 + jq * 3;
    const uint2* hp1 = h0b + (size_t)node1 * 12 + jq * 3;
#pragma unroll
    for (int q = 0; q < 3; q++) {
      uint2 u = hp0[q];
      h0v[q * 4 + 0] = blo(u.x); h0v[q * 4 + 1] = bhi(u.x);
      h0v[q * 4 + 2] = blo(u.y); h0v[q * 4 + 3] = bhi(u.y);
      uint2 w = hp1[q];
      h1v[q * 4 + 0] = blo(w.x); h1v[q * 4 + 1] = bhi(w.x);
      h1v[q * 4 + 2] = blo(w.y); h1v[q * 4 + 3] = bhi(w.y);
    }
    float o0[12], o1[12];
#pragma unroll
    for (int k = 0; k < HID; k++) {
      const float* wlr = swl + k * HID + jb;
      const float* wrr = swr + k * HID + jb;
      float s0 = 0.f, s1 = 0.f;
#pragma unroll
      for (int j = 0; j < 12; j++) {
        float wlv = wlr[j], wrv = wrr[j];
        s0 += a0[j] * wlv + h0v[j] * wrv;
        s1 += a1[j] * wlv + h1v[j] * wrv;
      }
      s0 += __shfl_xor(s0, 1); s0 += __shfl_xor(s0, 2);
      s1 += __shfl_xor(s1, 1); s1 += __shfl_xor(s1, 2);
      if (jq == (k / 12)) {
        o0[k % 12] = s0 + sbc[k];
        o1[k % 12] = s1 + sbc[k];
      }
    }
    float* d0 = hout + (size_t)node0 * HID + jb;
    float* d1 = hout + (size_t)node1 * HID + jb;
    *(float4*)(d0 + 0) = make_float4(o0[0], o0[1], o0[2], o0[3]);
    *(float4*)(d0 + 4) = make_float4(o0[4], o0[5], o0[6], o0[7]);
    *(float4*)(d0 + 8) = make_float4(o0[8], o0[9], o0[10], o0[11]);
    *(float4*)(d1 + 0) = make_float4(o1[0], o1[1], o1[2], o1[3]);
    *(float4*)(d1 + 4) = make_float4(o1[4], o1[5], o1[6], o1[7]);
    *(float4*)(d1 + 8) = make_float4(o1[8], o1[9], o1[10], o1[11]);
#pragma unroll
    for (int t = 0; t < 12; t++) {
      s[t] = o0[t] + o1[t];
      sq[t] = o0[t] * o0[t] + o1[t] * o1[t];
    }
  } else {
#pragma unroll
    for (int t = 0; t < 12; t++) { s[t] = 0.f; sq[t] = 0.f; }
  }
#pragma unroll
  for (int off = 4; off <= 32; off <<= 1) {
#pragma unroll
    for (int t = 0; t < 12; t++) {
      s[t] += __shfl_xor(s[t], off);
      sq[t] += __shfl_xor(sq[t], off);
    }
  }
  int lane = threadIdx.x & 63;
  if (lane < 4) {
#pragma unroll
    for (int t = 0; t < 12; t++) {
      atomicAdd(&ssum[lane * 12 + t], s[t]);
      atomicAdd(&ssq[lane * 12 + t], sq[t]);
    }
  }
  __syncthreads();
  if (threadIdx.x < 2 * HID)
    atomicAdd(&stats[threadIdx.x],
              threadIdx.x < HID ? ssum[threadIdx.x] : ssq[threadIdx.x - HID]);
}

// ==================================================================
// BN+ReLU+pool: 4 waves per graph, LDS cross-wave reduce
// ==================================================================
__global__ __launch_bounds__(256) void bn_pool_kernel(
    const float* __restrict__ hpre, const float* __restrict__ stats,
    const float* __restrict__ g, const float* __restrict__ be,
    const int* __restrict__ gstart,
    float* __restrict__ meanp, float* __restrict__ maxp) {
  __shared__ float sum_s[4][HID], max_s[4][HID];
  int gr = blockIdx.x;
  int w = threadIdx.x >> 6;
  int f = threadIdx.x & 63;
  int start = gstart[gr], end = gstart[gr + 1];
  if (f < HID) {
    float m = stats[f] * (1.0f / NNODES);
    float v = stats[HID + f] * (1.0f / NNODES) - m * m;
    float sc = g[f] * rsqrtf(v + CEPS);
    float sh = be[f] - m * sc;
    float sum = 0.f, mx = 0.f;
    for (int i = start + w; i < end; i += 4) {
      float val = fmaxf(hpre[(size_t)i * HID + f] * sc + sh, 0.f);
      sum += val;
      mx = fmaxf(mx, val);
    }
    sum_s[w][f] = sum;
    max_s[w][f] = mx;
  }
  __syncthreads();
  if (threadIdx.x < HID) {
    int k = threadIdx.x;
    float s = sum_s[0][k] + sum_s[1][k] + sum_s[2][k] + sum_s[3][k];
    float mx = fmaxf(fmaxf(max_s[0][k], max_s[1][k]), fmaxf(max_s[2][k], max_s[3][k]));
    float n = (float)(end - start);
    meanp[(size_t)gr * HID + k] = s / fmaxf(n, 1.0f);
    maxp[(size_t)gr * HID + k] = mx;
  }
}

// ==================================================================
// head
// ==================================================================
__global__ __launch_bounds__(64) void head1_kernel(
    const float* __restrict__ meanp, const float* __restrict__ maxp,
    const float* __restrict__ adme,
    const float* __restrict__ hw1, const float* __restrict__ hb1,
    float* __restrict__ z1) {
  int g = blockIdx.x;
  int t = threadIdx.x;
  __shared__ float comb[2 * HID + 20];
  if (t < HID) {
    comb[t] = meanp[(size_t)g * HID + t];
    comb[HID + t] = maxp[(size_t)g * HID + t];
  }
  if (t < 20) comb[2 * HID + t] = adme[(size_t)g * 20 + t];
  __syncthreads();
  float acc = hb1[t];
#pragma unroll
  for (int j = 0; j < 2 * HID + 20; j++) acc += comb[j] * hw1[t * (2 * HID + 20) + j];
  z1[(size_t)g * 64 + t] = acc;
}

__global__ __launch_bounds__(256) void headstats_kernel(
    const float* __restrict__ z1, const float* __restrict__ hg,
    const float* __restrict__ hbe, float* __restrict__ hsc, float* __restrict__ hsh) {
  int k = blockIdx.x;
  float s = 0.f, q = 0.f;
  for (int i = threadIdx.x; i < NGRAPHS; i += blockDim.x) {
    float v = z1[(size_t)i * 64 + k];
    s += v; q += v * v;
  }
  __shared__ float ls[4], lq[4];
  int lane = threadIdx.x & 63, w = threadIdx.x >> 6;
#pragma unroll
  for (int off = 32; off; off >>= 1) { s += __shfl_xor(s, off); q += __shfl_xor(q, off); }
  if (lane == 0) { ls[w] = s; lq[w] = q; }
  __syncthreads();
  if (threadIdx.x == 0) {
    s = ls[0] + ls[1] + ls[2] + ls[3];
    q = lq[0] + lq[1] + lq[2] + lq[3];
    float m = s * (1.0f / NGRAPHS);
    float v = q * (1.0f / NGRAPHS) - m * m;
    float sc = hg[k] * rsqrtf(v + CEPS);
    hsc[k] = sc; hsh[k] = hbe[k] - m * sc;
  }
}

__global__ __launch_bounds__(256) void head2_kernel(
    const float* __restrict__ z1, const float* __restrict__ hsc,
    const float* __restrict__ hsh, const float* __restrict__ hw2,
    const float* __restrict__ hb2, const float* __restrict__ hw3,
    const float* __restrict__ hb3, float* __restrict__ out) {
  __shared__ float sw2[32 * 64], sb2[32], sw3[32], ssc[64], ssh[64], sb3;
  for (int t = threadIdx.x; t < 32 * 64; t += blockDim.x) sw2[t] = hw2[t];
  if (threadIdx.x < 32) { sb2[threadIdx.x] = hb2[threadIdx.x]; sw3[threadIdx.x] = hw3[threadIdx.x]; }
  if (threadIdx.x < 64) { ssc[threadIdx.x] = hsc[threadIdx.x]; ssh[threadIdx.x] = hsh[threadIdx.x]; }
  if (threadIdx.x == 0) sb3 = hb3[0];
  __syncthreads();
  int g = blockIdx.x * blockDim.x + threadIdx.x;
  if (g >= NGRAPHS) return;
  float z[64];
#pragma unroll
  for (int k = 0; k < 64; k++) z[k] = fmaxf(z1[(size_t)g * 64 + k] * ssc[k] + ssh[k], 0.f);
  float o = sb3;
  for (int m = 0; m < 32; m++) {
    float a = sb2[m];
#pragma unroll
    for (int k = 0; k < 64; k++) a += z[k] * sw2[m * 64 + k];
    o += fmaxf(a, 0.f) * sw3[m];
  }
  out[g] = o;
}

// ==================================================================
// PATH B fallback kernels (two-pass CSR, f32; plain cnt semantics)
// ==================================================================
__global__ __launch_bounds__(256) void hist_kernel(
    const int* __restrict__ ei, int* __restrict__ cnt) {
  int t = blockIdx.x * blockDim.x + threadIdx.x;
  int e = t * 4;
  if (e >= NEDGES) return;
  int4 d4 = *(const int4*)(ei + NEDGES + e);
  atomicAdd(cnt + d4.x, 1);
  atomicAdd(cnt + d4.y, 1);
  atomicAdd(cnt + d4.z, 1);
  atomicAdd(cnt + d4.w, 1);
}

__global__ __launch_bounds__(256) void scan_bsum_kernel(
    const int* __restrict__ cnt, int* __restrict__ bsum) {
  __shared__ int s[256];
  int base = blockIdx.x * SCAN_CHUNK + threadIdx.x * 4;
  int t = 0;
#pragma unroll
  for (int k = 0; k < 4; k++) {
    int i = base + k;
    if (i < NNODES) t += cnt[i];
  }
  s[threadIdx.x] = t;
  __syncthreads();
  for (int off = 128; off; off >>= 1) {
    if (threadIdx.x < off) s[threadIdx.x] += s[threadIdx.x + off];
    __syncthreads();
  }
  if (threadIdx.x == 0) bsum[blockIdx.x] = s[0];
}

__global__ void scan_bsum_excl_kernel(int* __restrict__ bsum) {
  if (threadIdx.x == 0 && blockIdx.x == 0) {
    int acc = 0;
    for (int b = 0; b < NSCAN_BLOCKS; b++) {
      int v = bsum[b];
      bsum[b] = acc;
      acc += v;
    }
  }
}

__global__ __launch_bounds__(256) void scan_final_kernel(
    const int* __restrict__ cnt, const int* __restrict__ bsum,
    int* __restrict__ row_ptr, int* __restrict__ cursor) {
  __shared__ int s[256];
  int base = blockIdx.x * SCAN_CHUNK + threadIdx.x * 4;
  int c[4];
  int tsum = 0;
#pragma unroll
  for (int k = 0; k < 4; k++) {
    int i = base + k;
    c[k] = (i < NNODES) ? cnt[i] : 0;
    tsum += c[k];
  }
  s[threadIdx.x] = tsum;
  __syncthreads();
  for (int off = 1; off < 256; off <<= 1) {
    int x = 0;
    if (threadIdx.x >= off) x = s[threadIdx.x - off];
    __syncthreads();
    s[threadIdx.x] += x;
    __syncthreads();
  }
  int running = bsum[blockIdx.x] + s[threadIdx.x] - tsum;
#pragma unroll
  for (int k = 0; k < 4; k++) {
    int i = base + k;
    if (i < NNODES) {
      row_ptr[i] = running;
      cursor[i] = running;
      running += c[k];
    }
  }
}

__global__ __launch_bounds__(256) void fill_kernel(
    const int* __restrict__ ei, int* __restrict__ cursor,
    int* __restrict__ sorted_src) {
  int t = blockIdx.x * blockDim.x + threadIdx.x;
  int e = t * 4;
  if (e >= NEDGES) return;
  int4 s4 = *(const int4*)(ei + e);
  int4 d4 = *(const int4*)(ei + NEDGES + e);
  int p0 = atomicAdd(cursor + d4.x, 1);
  int p1 = atomicAdd(cursor + d4.y, 1);
  int p2 = atomicAdd(cursor + d4.z, 1);
  int p3 = atomicAdd(cursor + d4.w, 1);
  sorted_src[p0] = s4.x;
  sorted_src[p1] = s4.y;
  sorted_src[p2] = s4.z;
  sorted_src[p3] = s4.w;
}

__global__ __launch_bounds__(256) void agg0f_kernel(
    const float* __restrict__ x, const int* __restrict__ slots,
    const int* __restrict__ row_ptr, const int* __restrict__ cnt,
    float* __restrict__ agg) {
  int tid = blockIdx.x * blockDim.x + threadIdx.x;
  int node = tid / 3;
  int q = tid - node * 3;
  if (node >= NNODES) return;
  int start = row_ptr[node];
  int deg = cnt[node];
  float4 a0 = {0,0,0,0};
  for (int n = 0; n < deg; n++)
    f4add(a0, *(const float4*)(x + (size_t)slots[start + n] * INDIM + q * 4));
  float inv = 1.0f / fmaxf((float)deg, 1.0f);
  float4 r; r.x = a0.x * inv; r.y = a0.y * inv; r.z = a0.z * inv; r.w = a0.w * inv;
  *(float4*)(agg + (size_t)node * INDIM + q * 4) = r;
}

__global__ __launch_bounds__(256) void agg1f_kernel(
    const float* __restrict__ h0, const int* __restrict__ slots,
    const int* __restrict__ row_ptr, const int* __restrict__ cnt,
    float* __restrict__ agg) {
  int tid = blockIdx.x * blockDim.x + threadIdx.x;
  int node = tid / 12;
  int q = tid - node * 12;
  if (node >= NNODES) return;
  int start = row_ptr[node];
  int deg = cnt[node];
  float4 a0 = {0,0,0,0};
  for (int n = 0; n < deg; n++)
    f4add(a0, *(const float4*)(h0 + (size_t)slots[start + n] * HID + q * 4));
  float inv = 1.0f / fmaxf((float)deg, 1.0f);
  float4 r; r.x = a0.x * inv; r.y = a0.y * inv; r.z = a0.z * inv; r.w = a0.w * inv;
  *(float4*)(agg + (size_t)node * HID + q * 4) = r;
}

__global__ __launch_bounds__(256) void sage0_kernel(
    const float* __restrict__ x, const float* __restrict__ agg,
    const float* __restrict__ wl, const float* __restrict__ wr,
    const float* __restrict__ bc,
    float* __restrict__ hpre, float* __restrict__ stats) {
  __shared__ float swl[HID * INDIM], swr[HID * INDIM], sbc[HID];
  __shared__ float ssum[HID], ssq[HID];
  for (int t = threadIdx.x; t < HID * INDIM; t += blockDim.x) { swl[t] = wl[t]; swr[t] = wr[t]; }
  if (threadIdx.x < HID) { sbc[threadIdx.x] = bc[threadIdx.x]; ssum[threadIdx.x] = 0.f; ssq[threadIdx.x] = 0.f; }
  __syncthreads();
  int i = blockIdx.x * blockDim.x + threadIdx.x;
  bool valid = (i < NNODES);
  float xi[INDIM], ag[INDIM];
  if (valid) {
    const float4* xp = (const float4*)(x + (size_t)i * INDIM);
    const float4* mp = (const float4*)(agg + (size_t)i * INDIM);
#pragma unroll
    for (int q = 0; q < 3; q++) {
      float4 v = xp[q];
      xi[q * 4 + 0] = v.x; xi[q * 4 + 1] = v.y; xi[q * 4 + 2] = v.z; xi[q * 4 + 3] = v.w;
      float4 m = mp[q];
      ag[q * 4 + 0] = m.x; ag[q * 4 + 1] = m.y; ag[q * 4 + 2] = m.z; ag[q * 4 + 3] = m.w;
    }
  } else {
#pragma unroll
    for (int j = 0; j < INDIM; j++) { xi[j] = 0.f; ag[j] = 0.f; }
  }
  int lane = threadIdx.x & 63;
  for (int kb = 0; kb < HID; kb += 4) {
    float o[4];
#pragma unroll
    for (int t = 0; t < 4; t++) {
      int k = kb + t;
      float acc = valid ? sbc[k] : 0.f;
#pragma unroll
      for (int j = 0; j < INDIM; j++)
        acc += ag[j] * swl[k * INDIM + j] + xi[j] * swr[k * INDIM + j];
      o[t] = acc;
    }
    if (valid) {
      float4 v; v.x = o[0]; v.y = o[1]; v.z = o[2]; v.w = o[3];
      *((float4*)(hpre + (size_t)i * HID + kb)) = v;
    }
#pragma unroll
    for (int t = 0; t < 4; t++) {
      float s = o[t], q = o[t] * o[t];
#pragma unroll
      for (int off = 32; off; off >>= 1) { s += __shfl_xor(s, off); q += __shfl_xor(q, off); }
      if (lane == 0) { atomicAdd(&ssum[kb + t], s); atomicAdd(&ssq[kb + t], q); }
    }
  }
  __syncthreads();
  if (threadIdx.x < HID) {
    atomicAdd(&stats[threadIdx.x], ssum[threadIdx.x]);
    atomicAdd(&stats[HID + threadIdx.x], ssq[threadIdx.x]);
  }
}

__global__ __launch_bounds__(256) void bn_relu_kernel(
    float* __restrict__ h, const float* __restrict__ stats,
    const float* __restrict__ g, const float* __restrict__ be) {
  __shared__ float sc[HID], sh[HID];
  if (threadIdx.x < HID) {
    int k = threadIdx.x;
    float m = stats[k] * (1.0f / NNODES);
    float v = stats[HID + k] * (1.0f / NNODES) - m * m;
    float s = g[k] * rsqrtf(v + CEPS);
    sc[k] = s; sh[k] = be[k] - m * s;
  }
  __syncthreads();
  const int total = NNODES * (HID / 4);
  int stride = gridDim.x * blockDim.x;
  for (int idx = blockIdx.x * blockDim.x + threadIdx.x; idx < total; idx += stride) {
    int kb = (idx % (HID / 4)) * 4;
    float4 v = ((float4*)h)[idx];
    v.x = fmaxf(v.x * sc[kb + 0] + sh[kb + 0], 0.f);
    v.y = fmaxf(v.y * sc[kb + 1] + sh[kb + 1], 0.f);
    v.z = fmaxf(v.z * sc[kb + 2] + sh[kb + 2], 0.f);
    v.w = fmaxf(v.w * sc[kb + 3] + sh[kb + 3], 0.f);
    ((float4*)h)[idx] = v;
  }
}

__global__ __launch_bounds__(256) void sage1_kernel(
    const float* __restrict__ h0, float* __restrict__ agg_hpre,
    const float* __restrict__ wl, const float* __restrict__ wr,
    const float* __restrict__ bc, float* __restrict__ stats) {
  __shared__ float swl[HID * HID], swr[HID * HID], sbc[HID];
  __shared__ float ssum[HID], ssq[HID];
  for (int t = threadIdx.x; t < HID * HID; t += blockDim.x) { swl[t] = wl[t]; swr[t] = wr[t]; }
  if (threadIdx.x < HID) { sbc[threadIdx.x] = bc[threadIdx.x]; ssum[threadIdx.x] = 0.f; ssq[threadIdx.x] = 0.f; }
  __syncthreads();
  int i = blockIdx.x * blockDim.x + threadIdx.x;
  bool valid = (i < NNODES);
  float ag[HID], hx[HID];
  if (valid) {
    const float4* mp = (const float4*)(agg_hpre + (size_t)i * HID);
    const float4* hp = (const float4*)(h0 + (size_t)i * HID);
#pragma unroll
    for (int q = 0; q < HID / 4; q++) {
      float4 m = mp[q];
      ag[q * 4 + 0] = m.x; ag[q * 4 + 1] = m.y; ag[q * 4 + 2] = m.z; ag[q * 4 + 3] = m.w;
      float4 v = hp[q];
      hx[q * 4 + 0] = v.x; hx[q * 4 + 1] = v.y; hx[q * 4 + 2] = v.z; hx[q * 4 + 3] = v.w;
    }
  } else {
#pragma unroll
    for (int j = 0; j < HID; j++) { ag[j] = 0.f; hx[j] = 0.f; }
  }
  int lane = threadIdx.x & 63;
  for (int kb = 0; kb < HID; kb += 4) {
    float o[4];
#pragma unroll
    for (int t = 0; t < 4; t++) {
      int k = kb + t;
      float acc = valid ? sbc[k] : 0.f;
#pragma unroll
      for (int j = 0; j < HID; j++)
        acc += ag[j] * swl[k * HID + j] + hx[j] * swr[k * HID + j];
      o[t] = acc;
    }
    if (valid) {
      float4 v; v.x = o[0]; v.y = o[1]; v.z = o[2]; v.w = o[3];
      *((float4*)(agg_hpre + (size_t)i * HID + kb)) = v;
    }
#pragma unroll
    for (int t = 0; t < 4; t++) {
      float s = o[t], q = o[t] * o[t];
#pragma unroll
      for (int off = 32; off; off >>= 1) { s += __shfl_xor(s, off); q += __shfl_xor(q, off); }
      if (lane == 0) { atomicAdd(&ssum[kb + t], s); atomicAdd(&ssq[kb + t], q); }
    }
  }
  __syncthreads();
  if (threadIdx.x < HID) {
    atomicAdd(&stats[threadIdx.x], ssum[threadIdx.x]);
    atomicAdd(&stats[HID + threadIdx.x], ssq[threadIdx.x]);
  }
}

__global__ __launch_bounds__(64) void bn_pool1w_kernel(
    const float* __restrict__ hpre, const float* __restrict__ stats,
    const float* __restrict__ g, const float* __restrict__ be,
    const int* __restrict__ gstart,
    float* __restrict__ meanp, float* __restrict__ maxp) {
  int gr = blockIdx.x;
  int f = threadIdx.x;
  if (f >= HID) return;
  float m = stats[f] * (1.0f / NNODES);
  float v = stats[HID + f] * (1.0f / NNODES) - m * m;
  float sc = g[f] * rsqrtf(v + CEPS);
  float sh = be[f] - m * sc;
  int start = gstart[gr], end = gstart[gr + 1];
  float sum = 0.f, mx = 0.f;
  for (int i = start; i < end; i++) {
    float val = fmaxf(hpre[(size_t)i * HID + f] * sc + sh, 0.f);
    sum += val;
    mx = fmaxf(mx, val);
  }
  float n = (float)(end - start);
  meanp[(size_t)gr * HID + f] = sum / fmaxf(n, 1.0f);
  maxp[(size_t)gr * HID + f] = mx;
}

// ------------------------------------------------------------------
extern "C" void kernel_launch(void* const* d_in, const int* in_sizes, int n_in,
                              void* d_out, int out_size, void* d_ws, size_t ws_size,
                              hipStream_t stream) {
  (void)in_sizes; (void)n_in; (void)out_size;
  const float* x     = (const float*)d_in[0];
  const int*   ei    = (const int*)d_in[1];
  const int*   batch = (const int*)d_in[2];
  const float* adme  = (const float*)d_in[3];
  const float* wl0 = (const float*)d_in[4];
  const float* wr0 = (const float*)d_in[5];
  const float* bc0 = (const float*)d_in[6];
  const float* g0  = (const float*)d_in[7];
  const float* be0 = (const float*)d_in[8];
  const float* wl1 = (const float*)d_in[9];
  const float* wr1 = (const float*)d_in[10];
  const float* bc1 = (const float*)d_in[11];
  const float* g1  = (const float*)d_in[12];
  const float* be1 = (const float*)d_in[13];
  const float* hw1 = (const float*)d_in[14];
  const float* hb1 = (const float*)d_in[15];
  const float* hg1 = (const float*)d_in[16];
  const float* hbe1= (const float*)d_in[17];
  const float* hw2 = (const float*)d_in[18];
  const float* hb2 = (const float*)d_in[19];
  const float* hw3 = (const float*)d_in[20];
  const float* hb3 = (const float*)d_in[21];
  float* out = (float*)d_out;

  size_t elems_A = (size_t)NNODES * HID * 2 + (size_t)NNODES * CAP + 2048
                 + 512 + NNODES + 4 * HID
                 + (size_t)NGRAPHS * HID * 2 + (size_t)NGRAPHS * 64 + 128;
  bool padded = ws_size >= elems_A * 4 + 256;

  if (padded) {
    float* buf1 = (float*)d_ws;                            // [4.8M f32]
    float* buf2 = buf1 + (size_t)NNODES * HID;             // [4.8M f32]
    int* slots  = (int*)(buf2 + (size_t)NNODES * HID);     // [NNODES*CAP]
    int* gstart = slots + (size_t)NNODES * CAP;            // [2048]
    int* bucket_cursor = gstart + 2048;                    // [512]
    int* cnt    = bucket_cursor + 512;                     // [NNODES] tot|b1<<8|b2<<16|b3<<24
    float* stats0 = (float*)(cnt + NNODES);                // [2*HID]
    float* stats1 = stats0 + 2 * HID;                      // [2*HID]
    float* meanp = stats1 + 2 * HID;                       // [NGRAPHS*HID]
    float* maxp  = meanp + (size_t)NGRAPHS * HID;          // [NGRAPHS*HID]
    float* z1  = maxp + (size_t)NGRAPHS * HID;             // [NGRAPHS*64]
    float* hsc = z1 + (size_t)NGRAPHS * 64;                // [64]
    float* hsh = hsc + 64;                                 // [64]

    // overlays (timeline-disjoint):
    unsigned int* bucketed = (unsigned int*)buf2;          // live: p1 -> p2
    uint4* h0b = (uint4*)buf1;                             // bf16 h0: bn_relu_b16 -> sage1
    uint2* xb  = (uint2*)(buf1 + 4200000);                 // bf16 x: convert -> agg0

    hipMemsetAsync(bucket_cursor, 0, 512 * sizeof(int), stream);
    hipMemsetAsync(stats0, 0, 4 * HID * sizeof(float), stream);

    convert_x_kernel<<<(NNODES * INDIM / 8 + 255) / 256, 256, 0, stream>>>(x, (uint4*)xb);
    bucket_p1_kernel<<<P1_BLOCKS, P1_THREADS, 0, stream>>>(ei, bucket_cursor, bucketed);
    fill_p2_kernel<<<NBUCKET, 256, 0, stream>>>(bucketed, bucket_cursor, slots, cnt);
    graph_start_kernel<<<(NGRAPHS + 1 + 63) / 64, 64, 0, stream>>>(batch, gstart);

    // layer 0
    agg0_b_kernel<<<(NNODES * 3 + 255) / 256, 256, 0, stream>>>(xb, slots, cnt, buf1);
    sage0_4k_kernel<<<(NNODES * 4 + 255) / 256, 256, 0, stream>>>(x, buf1, wl0, wr0, bc0, buf2, stats0);
    bn_relu_b16_kernel<<<(NNODES * 6 + 255) / 256, 256, 0, stream>>>(buf2, stats0, g0, be0, h0b);

    // layer 1
    agg1_b_kernel<<<(NNODES * 6 + 255) / 256, 256, 0, stream>>>(h0b, slots, cnt, buf2);
    sage1_2n_kernel<<<(NNODES * 2 + 255) / 256, 256, 0, stream>>>(buf2, (const uint2*)h0b, wl1, wr1, bc1, buf2, stats1);
    bn_pool_kernel<<<NGRAPHS, 256, 0, stream>>>(buf2, stats1, g1, be1, gstart, meanp, maxp);

    // head
    head1_kernel<<<NGRAPHS, 64, 0, stream>>>(meanp, maxp, adme, hw1, hb1, z1);
    headstats_kernel<<<64, 256, 0, stream>>>(z1, hg1, hbe1, hsc, hsh);
    head2_kernel<<<(NGRAPHS + 255) / 256, 256, 0, stream>>>(z1, hsc, hsh, hw2, hb2, hw3, hb3, out);
  } else {
    // ----- Path B: two-pass CSR fallback (f32 end-to-end) -----
    float* buf1 = (float*)d_ws;
    float* buf2 = buf1 + (size_t)NNODES * HID;
    int* sorted_src = (int*)(buf2 + (size_t)NNODES * HID);
    int* row_ptr = sorted_src + NEDGES;
    int* cursor  = row_ptr + NNODES;
    int* bsum    = cursor + NNODES;
    int* gstart  = bsum + 128;
    int* cnt   = gstart + 2048;
    float* stats0 = (float*)(cnt + NNODES);
    float* stats1 = stats0 + 2 * HID;
    float* meanp = stats1 + 2 * HID;
    float* maxp  = meanp + (size_t)NGRAPHS * HID;
    float* z1  = maxp + (size_t)NGRAPHS * HID;
    float* hsc = z1 + (size_t)NGRAPHS * 64;
    float* hsh = hsc + 64;

    size_t zero_bytes = (char*)(stats1 + 2 * HID) - (char*)cnt;
    hipMemsetAsync(cnt, 0, zero_bytes, stream);

    hist_kernel<<<(NEDGES / 4 + 255) / 256, 256, 0, stream>>>(ei, cnt);
    scan_bsum_kernel<<<NSCAN_BLOCKS, 256, 0, stream>>>(cnt, bsum);
    scan_bsum_excl_kernel<<<1, 64, 0, stream>>>(bsum);
    scan_final_kernel<<<NSCAN_BLOCKS, 256, 0, stream>>>(cnt, bsum, row_ptr, cursor);
    fill_kernel<<<(NEDGES / 4 + 255) / 256, 256, 0, stream>>>(ei, cursor, sorted_src);
    graph_start_kernel<<<(NGRAPHS + 1 + 63) / 64, 64, 0, stream>>>(batch, gstart);

    agg0f_kernel<<<(NNODES * 3 + 255) / 256, 256, 0, stream>>>(x, sorted_src, row_ptr, cnt, buf1);
    sage0_kernel<<<(NNODES + 255) / 256, 256, 0, stream>>>(x, buf1, wl0, wr0, bc0, buf2, stats0);
    bn_relu_kernel<<<2048, 256, 0, stream>>>(buf2, stats0, g0, be0);

    agg1f_kernel<<<(NNODES * 12 + 255) / 256, 256, 0, stream>>>(buf2, sorted_src, row_ptr, cnt, buf1);
    sage1_kernel<<<(NNODES + 255) / 256, 256, 0, stream>>>(buf2, buf1, wl1, wr1, bc1, stats1);
    bn_pool1w_kernel<<<NGRAPHS, 64, 0, stream>>>(buf1, stats1, g1, be1, gstart, meanp, maxp);

    head1_kernel<<<NGRAPHS, 64, 0, stream>>>(meanp, maxp, adme, hw1, hb1, z1);
    headstats_kernel<<<64, 256, 0, stream>>>(z1, hg1, hbe1, hsc, hsh);
    head2_kernel<<<(NGRAPHS + 255) / 256, 256, 0, stream>>>(z1, hsc, hsh, hw2, hb2, hw3, hb3, out);
  }
}

// Round 14
// 272.433 us; speedup vs baseline: 1.0191x; 1.0191x over previous
//
#include <hip/hip_runtime.h>

#define NNODES  100000
#define NEDGES  3200000
#define NGRAPHS 2000
#define INDIM   12
#define HID     48
#define CEPS    1e-5f
#define CAP     96      // padded per-node slot capacity

#define BSHIFT   8
#define NBUCKET  ((NNODES + 255) / 256)     // 391 buckets of 256 nodes
#define CAPB     8704
#define P1_BLOCKS 250
#define P1_THREADS 1024
#define P1_EDGES (NEDGES / P1_BLOCKS)       // 12800 edges per block
#define GSHIFT   15                         // 4 src groups of 32768 nodes (3.1MB bf16 h0 each)

#define SCAN_CHUNK 1024
#define NSCAN_BLOCKS ((NNODES + SCAN_CHUNK - 1) / SCAN_CHUNK)

__device__ inline void f4add(float4& a, const float4 b) {
  a.x += b.x; a.y += b.y; a.z += b.z; a.w += b.w;
}
__device__ inline float blo(unsigned u) { return __uint_as_float(u << 16); }
__device__ inline float bhi(unsigned u) { return __uint_as_float(u & 0xffff0000u); }
__device__ inline unsigned bpack(float a, float b) {
  unsigned ua = __float_as_uint(a), ub = __float_as_uint(b);
  ua = (ua + 0x7fffu + ((ua >> 16) & 1u)) >> 16;
  ub = (ub + 0x7fffu + ((ub >> 16) & 1u)) >> 16;
  return ua | (ub << 16);
}

// ==================================================================
// x -> bf16 copy
// ==================================================================
__global__ __launch_bounds__(256) void convert_x_kernel(
    const float* __restrict__ x, uint4* __restrict__ xb) {
  int idx = blockIdx.x * blockDim.x + threadIdx.x;
  if (idx >= NNODES * INDIM / 8) return;
  const float4* p = (const float4*)(x + (size_t)idx * 8);
  float4 v0 = p[0], v1 = p[1];
  uint4 o;
  o.x = bpack(v0.x, v0.y); o.y = bpack(v0.z, v0.w);
  o.z = bpack(v1.x, v1.y); o.w = bpack(v1.z, v1.w);
  xb[idx] = o;
}

// ==================================================================
// phase 1: bucket edges by dst>>8 (packed (dstlocal<<24)|src)
// ==================================================================
__global__ __launch_bounds__(P1_THREADS) void bucket_p1_kernel(
    const int* __restrict__ ei, int* __restrict__ bucket_cursor,
    unsigned int* __restrict__ bucketed) {
  __shared__ int hist[NBUCKET];
  __shared__ int lcur[NBUCKET];
  for (int b = threadIdx.x; b < NBUCKET; b += P1_THREADS) hist[b] = 0;
  __syncthreads();
  const int base = blockIdx.x * P1_EDGES;
  for (int off = threadIdx.x * 4; off < P1_EDGES; off += P1_THREADS * 4) {
    int4 d4 = *(const int4*)(ei + NEDGES + base + off);
    atomicAdd(&hist[(d4.x >> BSHIFT) % NBUCKET], 1);
    atomicAdd(&hist[(d4.y >> BSHIFT) % NBUCKET], 1);
    atomicAdd(&hist[(d4.z >> BSHIFT) % NBUCKET], 1);
    atomicAdd(&hist[(d4.w >> BSHIFT) % NBUCKET], 1);
  }
  __syncthreads();
  for (int b = threadIdx.x; b < NBUCKET; b += P1_THREADS)
    lcur[b] = (hist[b] > 0) ? atomicAdd(&bucket_cursor[b], hist[b]) : 0;
  __syncthreads();
  for (int off = threadIdx.x * 4; off < P1_EDGES; off += P1_THREADS * 4) {
    int4 s4 = *(const int4*)(ei + base + off);
    int4 d4 = *(const int4*)(ei + NEDGES + base + off);
    {
      int b0 = (d4.x >> BSHIFT) % NBUCKET; int p = atomicAdd(&lcur[b0], 1);
      if ((unsigned)p < (unsigned)CAPB)
        bucketed[(size_t)b0 * CAPB + p] = ((unsigned)(d4.x & 255) << 24) | ((unsigned)s4.x & 0xFFFFFFu);
    }
    {
      int b1 = (d4.y >> BSHIFT) % NBUCKET; int p = atomicAdd(&lcur[b1], 1);
      if ((unsigned)p < (unsigned)CAPB)
        bucketed[(size_t)b1 * CAPB + p] = ((unsigned)(d4.y & 255) << 24) | ((unsigned)s4.y & 0xFFFFFFu);
    }
    {
      int b2 = (d4.z >> BSHIFT) % NBUCKET; int p = atomicAdd(&lcur[b2], 1);
      if ((unsigned)p < (unsigned)CAPB)
        bucketed[(size_t)b2 * CAPB + p] = ((unsigned)(d4.z & 255) << 24) | ((unsigned)s4.z & 0xFFFFFFu);
    }
    {
      int b3 = (d4.w >> BSHIFT) % NBUCKET; int p = atomicAdd(&lcur[b3], 1);
      if ((unsigned)p < (unsigned)CAPB)
        bucketed[(size_t)b3 * CAPB + p] = ((unsigned)(d4.w & 255) << 24) | ((unsigned)s4.w & 0xFFFFFFu);
    }
  }
}

// ==================================================================
// phase 2: one block per bucket; LDS-cached bucket (single global
// read) + 4-group counting sort by src>>15.
// cnt = total | b1<<8 | b2<<16 | b3<<24
// ==================================================================
__global__ __launch_bounds__(256) void fill_p2_kernel(
    const unsigned int* __restrict__ bucketed, const int* __restrict__ bucket_cursor,
    int* __restrict__ slots, int* __restrict__ cnt) {
  __shared__ unsigned lbuck[CAPB];
  __shared__ int cbase[256][4];
  __shared__ int ccur[256][4];
#pragma unroll
  for (int g = 0; g < 4; g++) { cbase[threadIdx.x][g] = 0; ccur[threadIdx.x][g] = 0; }
  __syncthreads();
  int b = blockIdx.x;
  int count = bucket_cursor[b];
  if (count > CAPB) count = CAPB;
  size_t bb = (size_t)b * CAPB;
  // coalesced single global read into LDS
  for (int i = threadIdx.x; i < count; i += 256) lbuck[i] = bucketed[bb + i];
  __syncthreads();
  // pass 1: counts per (dstlocal, group), from LDS
  for (int i = threadIdx.x; i < count; i += 256) {
    unsigned v = lbuck[i];
    atomicAdd(&cbase[v >> 24][(v & 0xFFFFFFu) >> GSHIFT], 1);
  }
  __syncthreads();
  // per-node exclusive bases, clamped at CAP
  {
    int dl = threadIdx.x;
    int c0 = cbase[dl][0], c1 = cbase[dl][1], c2 = cbase[dl][2], c3 = cbase[dl][3];
    int b1 = min(c0, CAP);
    int b2 = min(c0 + c1, CAP);
    int b3 = min(c0 + c1 + c2, CAP);
    int tot = min(c0 + c1 + c2 + c3, CAP);
    cbase[dl][0] = 0; cbase[dl][1] = b1; cbase[dl][2] = b2; cbase[dl][3] = b3;
    int node = b * 256 + dl;
    if (node < NNODES) cnt[node] = tot | (b1 << 8) | (b2 << 16) | (b3 << 24);
  }
  __syncthreads();
  // pass 2: scatter sorted by group, from LDS
  for (int i = threadIdx.x; i < count; i += 256) {
    unsigned v = lbuck[i];
    int dl = (int)(v >> 24);
    int s = (int)(v & 0xFFFFFFu);
    int g = s >> GSHIFT;
    int node = b * 256 + dl;
    if (node < NNODES) {
      int p = cbase[dl][g] + atomicAdd(&ccur[dl][g], 1);
      if (p < CAP) slots[(size_t)node * CAP + p] = s;
    }
  }
}

// ==================================================================
// graph segment starts
// ==================================================================
__global__ __launch_bounds__(64) void graph_start_kernel(
    const int* __restrict__ batch, int* __restrict__ gstart) {
  int g = blockIdx.x * blockDim.x + threadIdx.x;
  if (g > NGRAPHS) return;
  int lo = 0, hi = NNODES;
  while (lo < hi) {
    int mid = (lo + hi) >> 1;
    if (batch[mid] < g) lo = mid + 1; else hi = mid;
  }
  gstart[g] = lo;
}

// ==================================================================
// agg0: bf16 gather, 3 lanes/node. xb is 2.4MB (L2-fit) -> single loop.
// ==================================================================
#define GATH24(BEGIN, COUNT)                                              \
  {                                                                       \
    int n = 0;                                                            \
    for (; n + 4 <= (COUNT); n += 4) {                                    \
      int sa = slots[(BEGIN) + n + 0];                                    \
      int sb = slots[(BEGIN) + n + 1];                                    \
      int sc = slots[(BEGIN) + n + 2];                                    \
      int sd = slots[(BEGIN) + n + 3];                                    \
      uint2 ua = xb[(size_t)sa * 3 + q];                                  \
      uint2 ub = xb[(size_t)sb * 3 + q];                                  \
      uint2 uc = xb[(size_t)sc * 3 + q];                                  \
      uint2 ud = xb[(size_t)sd * 3 + q];                                  \
      a0[0] += blo(ua.x); a0[1] += bhi(ua.x); a0[2] += blo(ua.y); a0[3] += bhi(ua.y); \
      a1[0] += blo(ub.x); a1[1] += bhi(ub.x); a1[2] += blo(ub.y); a1[3] += bhi(ub.y); \
      a2[0] += blo(uc.x); a2[1] += bhi(uc.x); a2[2] += blo(uc.y); a2[3] += bhi(uc.y); \
      a3[0] += blo(ud.x); a3[1] += bhi(ud.x); a3[2] += blo(ud.y); a3[3] += bhi(ud.y); \
    }                                                                     \
    for (; n < (COUNT); n++) {                                            \
      uint2 u = xb[(size_t)slots[(BEGIN) + n] * 3 + q];                   \
      a0[0] += blo(u.x); a0[1] += bhi(u.x); a0[2] += blo(u.y); a0[3] += bhi(u.y); \
    }                                                                     \
  }

__global__ __launch_bounds__(256) void agg0_b_kernel(
    const uint2* __restrict__ xb, const int* __restrict__ slots,
    const int* __restrict__ cnt, float* __restrict__ agg) {
  int tid = blockIdx.x * blockDim.x + threadIdx.x;
  int node = tid / 3;
  int q = tid - node * 3;
  if (node >= NNODES) return;
  size_t start = (size_t)node * CAP;
  int tot = cnt[node] & 0xFF;
  float a0[4] = {0,0,0,0}, a1[4] = {0,0,0,0}, a2[4] = {0,0,0,0}, a3[4] = {0,0,0,0};
  GATH24(start, tot);
  float inv = 1.0f / fmaxf((float)tot, 1.0f);
  float4 r;
  r.x = (a0[0] + a1[0] + a2[0] + a3[0]) * inv;
  r.y = (a0[1] + a1[1] + a2[1] + a3[1]) * inv;
  r.z = (a0[2] + a1[2] + a2[2] + a3[2]) * inv;
  r.w = (a0[3] + a1[3] + a2[3] + a3[3]) * inv;
  *(float4*)(agg + (size_t)node * INDIM + q * 4) = r;
}

// ==================================================================
// sage0 (k-quarter split) + stats via lane butterfly
// ==================================================================
__global__ __launch_bounds__(256) void sage0_4k_kernel(
    const float* __restrict__ x, const float* __restrict__ agg,
    const float* __restrict__ wl, const float* __restrict__ wr,
    const float* __restrict__ bc, float* __restrict__ hpre,
    float* __restrict__ stats) {
  __shared__ float swl[HID * INDIM], swr[HID * INDIM], sbc[HID];
  __shared__ float ssum[HID], ssq[HID];
  for (int t = threadIdx.x; t < HID * INDIM; t += 256) { swl[t] = wl[t]; swr[t] = wr[t]; }
  if (threadIdx.x < HID) {
    sbc[threadIdx.x] = bc[threadIdx.x];
    ssum[threadIdx.x] = 0.f; ssq[threadIdx.x] = 0.f;
  }
  __syncthreads();
  int tid = blockIdx.x * 256 + threadIdx.x;
  int node = tid >> 2;
  int kq = tid & 3;
  bool valid = (node < NNODES);
  float s[12], sq[12];
  if (valid) {
    float xi[INDIM], ag[INDIM];
    const float4* xp = (const float4*)(x + (size_t)node * INDIM);
    const float4* mp = (const float4*)(agg + (size_t)node * INDIM);
#pragma unroll
    for (int q = 0; q < 3; q++) {
      float4 v = xp[q];
      xi[q * 4 + 0] = v.x; xi[q * 4 + 1] = v.y; xi[q * 4 + 2] = v.z; xi[q * 4 + 3] = v.w;
      float4 m = mp[q];
      ag[q * 4 + 0] = m.x; ag[q * 4 + 1] = m.y; ag[q * 4 + 2] = m.z; ag[q * 4 + 3] = m.w;
    }
    float o[12];
#pragma unroll
    for (int t = 0; t < 12; t++) {
      int k = kq * 12 + t;
      const float* wlr = swl + k * INDIM;
      const float* wrr = swr + k * INDIM;
      float acc = sbc[k];
#pragma unroll
      for (int j = 0; j < INDIM; j++) acc += ag[j] * wlr[j] + xi[j] * wrr[j];
      o[t] = acc;
    }
    float* dst = hpre + (size_t)node * HID + kq * 12;
    *(float4*)(dst + 0) = make_float4(o[0], o[1], o[2], o[3]);
    *(float4*)(dst + 4) = make_float4(o[4], o[5], o[6], o[7]);
    *(float4*)(dst + 8) = make_float4(o[8], o[9], o[10], o[11]);
#pragma unroll
    for (int t = 0; t < 12; t++) { s[t] = o[t]; sq[t] = o[t] * o[t]; }
  } else {
#pragma unroll
    for (int t = 0; t < 12; t++) { s[t] = 0.f; sq[t] = 0.f; }
  }
#pragma unroll
  for (int off = 4; off <= 32; off <<= 1) {
#pragma unroll
    for (int t = 0; t < 12; t++) {
      s[t] += __shfl_xor(s[t], off);
      sq[t] += __shfl_xor(sq[t], off);
    }
  }
  int lane = threadIdx.x & 63;
  if (lane < 4) {
#pragma unroll
    for (int t = 0; t < 12; t++) {
      atomicAdd(&ssum[lane * 12 + t], s[t]);
      atomicAdd(&ssq[lane * 12 + t], sq[t]);
    }
  }
  __syncthreads();
  if (threadIdx.x < 2 * HID)
    atomicAdd(&stats[threadIdx.x],
              threadIdx.x < HID ? ssum[threadIdx.x] : ssq[threadIdx.x - HID]);
}

// ==================================================================
// BN+ReLU -> bf16
// ==================================================================
__global__ __launch_bounds__(256) void bn_relu_b16_kernel(
    const float* __restrict__ hpre, const float* __restrict__ stats,
    const float* __restrict__ g, const float* __restrict__ be,
    uint4* __restrict__ h0b) {
  __shared__ float sc[HID], sh[HID];
  if (threadIdx.x < HID) {
    int k = threadIdx.x;
    float m = stats[k] * (1.0f / NNODES);
    float v = stats[HID + k] * (1.0f / NNODES) - m * m;
    float s = g[k] * rsqrtf(v + CEPS);
    sc[k] = s; sh[k] = be[k] - m * s;
  }
  __syncthreads();
  int idx = blockIdx.x * 256 + threadIdx.x;
  if (idx >= NNODES * 6) return;
  const float4* p = (const float4*)(hpre + (size_t)idx * 8);
  float4 v0 = p[0], v1 = p[1];
  int kb = (idx % 6) * 8;
  float r0 = fmaxf(v0.x * sc[kb + 0] + sh[kb + 0], 0.f);
  float r1 = fmaxf(v0.y * sc[kb + 1] + sh[kb + 1], 0.f);
  float r2 = fmaxf(v0.z * sc[kb + 2] + sh[kb + 2], 0.f);
  float r3 = fmaxf(v0.w * sc[kb + 3] + sh[kb + 3], 0.f);
  float r4 = fmaxf(v1.x * sc[kb + 4] + sh[kb + 4], 0.f);
  float r5 = fmaxf(v1.y * sc[kb + 5] + sh[kb + 5], 0.f);
  float r6 = fmaxf(v1.z * sc[kb + 6] + sh[kb + 6], 0.f);
  float r7 = fmaxf(v1.w * sc[kb + 7] + sh[kb + 7], 0.f);
  uint4 o;
  o.x = bpack(r0, r1); o.y = bpack(r2, r3); o.z = bpack(r4, r5); o.w = bpack(r6, r7);
  h0b[idx] = o;
}

// ==================================================================
// agg1: bf16 gather, 6 lanes/node, FOUR src-group segment sweeps
// ==================================================================
#define GATH48(BEGIN, COUNT)                                              \
  {                                                                       \
    int n = 0;                                                            \
    for (; n + 4 <= (COUNT); n += 4) {                                    \
      int sa = slots[(BEGIN) + n + 0];                                    \
      int sb = slots[(BEGIN) + n + 1];                                    \
      int sc = slots[(BEGIN) + n + 2];                                    \
      int sd = slots[(BEGIN) + n + 3];                                    \
      uint4 ua = h0b[(size_t)sa * 6 + q];                                 \
      uint4 ub = h0b[(size_t)sb * 6 + q];                                 \
      uint4 uc = h0b[(size_t)sc * 6 + q];                                 \
      uint4 ud = h0b[(size_t)sd * 6 + q];                                 \
      a0[0] += blo(ua.x); a0[1] += bhi(ua.x); a0[2] += blo(ua.y); a0[3] += bhi(ua.y); \
      a0[4] += blo(ua.z); a0[5] += bhi(ua.z); a0[6] += blo(ua.w); a0[7] += bhi(ua.w); \
      a1[0] += blo(ub.x); a1[1] += bhi(ub.x); a1[2] += blo(ub.y); a1[3] += bhi(ub.y); \
      a1[4] += blo(ub.z); a1[5] += bhi(ub.z); a1[6] += blo(ub.w); a1[7] += bhi(ub.w); \
      a2[0] += blo(uc.x); a2[1] += bhi(uc.x); a2[2] += blo(uc.y); a2[3] += bhi(uc.y); \
      a2[4] += blo(uc.z); a2[5] += bhi(uc.z); a2[6] += blo(uc.w); a2[7] += bhi(uc.w); \
      a3[0] += blo(ud.x); a3[1] += bhi(ud.x); a3[2] += blo(ud.y); a3[3] += bhi(ud.y); \
      a3[4] += blo(ud.z); a3[5] += bhi(ud.z); a3[6] += blo(ud.w); a3[7] += bhi(ud.w); \
    }                                                                     \
    for (; n < (COUNT); n++) {                                            \
      uint4 u = h0b[(size_t)slots[(BEGIN) + n] * 6 + q];                  \
      a0[0] += blo(u.x); a0[1] += bhi(u.x); a0[2] += blo(u.y); a0[3] += bhi(u.y); \
      a0[4] += blo(u.z); a0[5] += bhi(u.z); a0[6] += blo(u.w); a0[7] += bhi(u.w); \
    }                                                                     \
  }

__global__ __launch_bounds__(256) void agg1_b_kernel(
    const uint4* __restrict__ h0b, const int* __restrict__ slots,
    const int* __restrict__ cnt, float* __restrict__ agg) {
  int tid = blockIdx.x * blockDim.x + threadIdx.x;
  int node = tid / 6;
  int q = tid - node * 6;
  if (node >= NNODES) return;
  size_t start = (size_t)node * CAP;
  int packed = cnt[node];
  int tot = packed & 0xFF;
  int b1 = (packed >> 8) & 0xFF;
  int b2 = (packed >> 16) & 0xFF;
  int b3 = (packed >> 24) & 0xFF;
  float a0[8] = {0,0,0,0,0,0,0,0}, a1[8] = {0,0,0,0,0,0,0,0};
  float a2[8] = {0,0,0,0,0,0,0,0}, a3[8] = {0,0,0,0,0,0,0,0};
  GATH48(start, b1);
  GATH48(start + b1, b2 - b1);
  GATH48(start + b2, b3 - b2);
  GATH48(start + b3, tot - b3);
  float inv = 1.0f / fmaxf((float)tot, 1.0f);
  float* dst = agg + (size_t)node * HID + q * 8;
  float4 r0, r1;
  r0.x = (a0[0] + a1[0] + a2[0] + a3[0]) * inv;
  r0.y = (a0[1] + a1[1] + a2[1] + a3[1]) * inv;
  r0.z = (a0[2] + a1[2] + a2[2] + a3[2]) * inv;
  r0.w = (a0[3] + a1[3] + a2[3] + a3[3]) * inv;
  r1.x = (a0[4] + a1[4] + a2[4] + a3[4]) * inv;
  r1.y = (a0[5] + a1[5] + a2[5] + a3[5]) * inv;
  r1.z = (a0[6] + a1[6] + a2[6] + a3[6]) * inv;
  r1.w = (a0[7] + a1[7] + a2[7] + a3[7]) * inv;
  *(float4*)(dst + 0) = r0;
  *(float4*)(dst + 4) = r1;
}

// ==================================================================
// sage1 (2 nodes/thread, j-quarter split, shfl reduce) + butterfly stats
// ==================================================================
__global__ __launch_bounds__(256) void sage1_2n_kernel(
    const float* __restrict__ agg, const uint2* __restrict__ h0b,
    const float* __restrict__ wl, const float* __restrict__ wr,
    const float* __restrict__ bc, float* __restrict__ hout,
    float* __restrict__ stats) {
  __shared__ float swl[HID * HID], swr[HID * HID], sbc[HID];
  __shared__ float ssum[HID], ssq[HID];
  for (int t = threadIdx.x; t < HID * HID; t += 256) { swl[t] = wl[t]; swr[t] = wr[t]; }
  if (threadIdx.x < HID) {
    sbc[threadIdx.x] = bc[threadIdx.x];
    ssum[threadIdx.x] = 0.f; ssq[threadIdx.x] = 0.f;
  }
  __syncthreads();
  int tid = blockIdx.x * 256 + threadIdx.x;
  int p = tid >> 2;
  int jq = tid & 3;
  bool valid = (p < NNODES / 2);
  const int jb = jq * 12;
  float s[12], sq[12];
  if (valid) {
    int node0 = 2 * p, node1 = 2 * p + 1;
    float a0[12], a1[12], h0v[12], h1v[12];
    const float4* ap0 = (const float4*)(agg + (size_t)node0 * HID + jb);
    const float4* ap1 = (const float4*)(agg + (size_t)node1 * HID + jb);
#pragma unroll
    for (int q = 0; q < 3; q++) {
      float4 v = ap0[q];
      a0[q * 4 + 0] = v.x; a0[q * 4 + 1] = v.y; a0[q * 4 + 2] = v.z; a0[q * 4 + 3] = v.w;
      float4 w = ap1[q];
      a1[q * 4 + 0] = w.x; a1[q * 4 + 1] = w.y; a1[q * 4 + 2] = w.z; a1[q * 4 + 3] = w.w;
    }
    const uint2* hp0 = h0b + (size_t)node0 * 12 + jq * 3;
    const uint2* hp1 = h0b + (size_t)node1 * 12 + jq * 3;
#pragma unroll
    for (int q = 0; q < 3; q++) {
      uint2 u = hp0[q];
      h0v[q * 4 + 0] = blo(u.x); h0v[q * 4 + 1] = bhi(u.x);
      h0v[q * 4 + 2] = blo(u.y); h0v[q * 4 + 3] = bhi(u.y);
      uint2 w = hp1[q];
      h1v[q * 4 + 0] = blo(w.x); h1v[q * 4 + 1] = bhi(w.x);
      h1v[q * 4 + 2] = blo(w.y); h1v[q * 4 + 3] = bhi(w.y);
    }
    float o0[12], o1[12];
#pragma unroll
    for (int k = 0; k < HID; k++) {
      const float* wlr = swl + k * HID + jb;
      const float* wrr = swr + k * HID + jb;
      float s0 = 0.f, s1 = 0.f;
#pragma unroll
      for (int j = 0; j < 12; j++) {
        float wlv = wlr[j], wrv = wrr[j];
        s0 += a0[j] * wlv + h0v[j] * wrv;
        s1 += a1[j] * wlv + h1v[j] * wrv;
      }
      s0 += __shfl_xor(s0, 1); s0 += __shfl_xor(s0, 2);
      s1 += __shfl_xor(s1, 1); s1 += __shfl_xor(s1, 2);
      if (jq == (k / 12)) {
        o0[k % 12] = s0 + sbc[k];
        o1[k % 12] = s1 + sbc[k];
      }
    }
    float* d0 = hout + (size_t)node0 * HID + jb;
    float* d1 = hout + (size_t)node1 * HID + jb;
    *(float4*)(d0 + 0) = make_float4(o0[0], o0[1], o0[2], o0[3]);
    *(float4*)(d0 + 4) = make_float4(o0[4], o0[5], o0[6], o0[7]);
    *(float4*)(d0 + 8) = make_float4(o0[8], o0[9], o0[10], o0[11]);
    *(float4*)(d1 + 0) = make_float4(o1[0], o1[1], o1[2], o1[3]);
    *(float4*)(d1 + 4) = make_float4(o1[4], o1[5], o1[6], o1[7]);
    *(float4*)(d1 + 8) = make_float4(o1[8], o1[9], o1[10], o1[11]);
#pragma unroll
    for (int t = 0; t < 12; t++) {
      s[t] = o0[t] + o1[t];
      sq[t] = o0[t] * o0[t] + o1[t] * o1[t];
    }
  } else {
#pragma unroll
    for (int t = 0; t < 12; t++) { s[t] = 0.f; sq[t] = 0.f; }
  }
#pragma unroll
  for (int off = 4; off <= 32; off <<= 1) {
#pragma unroll
    for (int t = 0; t < 12; t++) {
      s[t] += __shfl_xor(s[t], off);
      sq[t] += __shfl_xor(sq[t], off);
    }
  }
  int lane = threadIdx.x & 63;
  if (lane < 4) {
#pragma unroll
    for (int t = 0; t < 12; t++) {
      atomicAdd(&ssum[lane * 12 + t], s[t]);
      atomicAdd(&ssq[lane * 12 + t], sq[t]);
    }
  }
  __syncthreads();
  if (threadIdx.x < 2 * HID)
    atomicAdd(&stats[threadIdx.x],
              threadIdx.x < HID ? ssum[threadIdx.x] : ssq[threadIdx.x - HID]);
}

// ==================================================================
// BN+ReLU+pool: 4 waves per graph, LDS cross-wave reduce
// ==================================================================
__global__ __launch_bounds__(256) void bn_pool_kernel(
    const float* __restrict__ hpre, const float* __restrict__ stats,
    const float* __restrict__ g, const float* __restrict__ be,
    const int* __restrict__ gstart,
    float* __restrict__ meanp, float* __restrict__ maxp) {
  __shared__ float sum_s[4][HID], max_s[4][HID];
  int gr = blockIdx.x;
  int w = threadIdx.x >> 6;
  int f = threadIdx.x & 63;
  int start = gstart[gr], end = gstart[gr + 1];
  if (f < HID) {
    float m = stats[f] * (1.0f / NNODES);
    float v = stats[HID + f] * (1.0f / NNODES) - m * m;
    float sc = g[f] * rsqrtf(v + CEPS);
    float sh = be[f] - m * sc;
    float sum = 0.f, mx = 0.f;
    for (int i = start + w; i < end; i += 4) {
      float val = fmaxf(hpre[(size_t)i * HID + f] * sc + sh, 0.f);
      sum += val;
      mx = fmaxf(mx, val);
    }
    sum_s[w][f] = sum;
    max_s[w][f] = mx;
  }
  __syncthreads();
  if (threadIdx.x < HID) {
    int k = threadIdx.x;
    float s = sum_s[0][k] + sum_s[1][k] + sum_s[2][k] + sum_s[3][k];
    float mx = fmaxf(fmaxf(max_s[0][k], max_s[1][k]), fmaxf(max_s[2][k], max_s[3][k]));
    float n = (float)(end - start);
    meanp[(size_t)gr * HID + k] = s / fmaxf(n, 1.0f);
    maxp[(size_t)gr * HID + k] = mx;
  }
}

// ==================================================================
// head
// ==================================================================
__global__ __launch_bounds__(64) void head1_kernel(
    const float* __restrict__ meanp, const float* __restrict__ maxp,
    const float* __restrict__ adme,
    const float* __restrict__ hw1, const float* __restrict__ hb1,
    float* __restrict__ z1) {
  int g = blockIdx.x;
  int t = threadIdx.x;
  __shared__ float comb[2 * HID + 20];
  if (t < HID) {
    comb[t] = meanp[(size_t)g * HID + t];
    comb[HID + t] = maxp[(size_t)g * HID + t];
  }
  if (t < 20) comb[2 * HID + t] = adme[(size_t)g * 20 + t];
  __syncthreads();
  float acc = hb1[t];
#pragma unroll
  for (int j = 0; j < 2 * HID + 20; j++) acc += comb[j] * hw1[t * (2 * HID + 20) + j];
  z1[(size_t)g * 64 + t] = acc;
}

__global__ __launch_bounds__(256) void headstats_kernel(
    const float* __restrict__ z1, const float* __restrict__ hg,
    const float* __restrict__ hbe, float* __restrict__ hsc, float* __restrict__ hsh) {
  int k = blockIdx.x;
  float s = 0.f, q = 0.f;
  for (int i = threadIdx.x; i < NGRAPHS; i += blockDim.x) {
    float v = z1[(size_t)i * 64 + k];
    s += v; q += v * v;
  }
  __shared__ float ls[4], lq[4];
  int lane = threadIdx.x & 63, w = threadIdx.x >> 6;
#pragma unroll
  for (int off = 32; off; off >>= 1) { s += __shfl_xor(s, off); q += __shfl_xor(q, off); }
  if (lane == 0) { ls[w] = s; lq[w] = q; }
  __syncthreads();
  if (threadIdx.x == 0) {
    s = ls[0] + ls[1] + ls[2] + ls[3];
    q = lq[0] + lq[1] + lq[2] + lq[3];
    float m = s * (1.0f / NGRAPHS);
    float v = q * (1.0f / NGRAPHS) - m * m;
    float sc = hg[k] * rsqrtf(v + CEPS);
    hsc[k] = sc; hsh[k] = hbe[k] - m * sc;
  }
}

__global__ __launch_bounds__(256) void head2_kernel(
    const float* __restrict__ z1, const float* __restrict__ hsc,
    const float* __restrict__ hsh, const float* __restrict__ hw2,
    const float* __restrict__ hb2, const float* __restrict__ hw3,
    const float* __restrict__ hb3, float* __restrict__ out) {
  __shared__ float sw2[32 * 64], sb2[32], sw3[32], ssc[64], ssh[64], sb3;
  for (int t = threadIdx.x; t < 32 * 64; t += blockDim.x) sw2[t] = hw2[t];
  if (threadIdx.x < 32) { sb2[threadIdx.x] = hb2[threadIdx.x]; sw3[threadIdx.x] = hw3[threadIdx.x]; }
  if (threadIdx.x < 64) { ssc[threadIdx.x] = hsc[threadIdx.x]; ssh[threadIdx.x] = hsh[threadIdx.x]; }
  if (threadIdx.x == 0) sb3 = hb3[0];
  __syncthreads();
  int g = blockIdx.x * blockDim.x + threadIdx.x;
  if (g >= NGRAPHS) return;
  float z[64];
#pragma unroll
  for (int k = 0; k < 64; k++) z[k] = fmaxf(z1[(size_t)g * 64 + k] * ssc[k] + ssh[k], 0.f);
  float o = sb3;
  for (int m = 0; m < 32; m++) {
    float a = sb2[m];
#pragma unroll
    for (int k = 0; k < 64; k++) a += z[k] * sw2[m * 64 + k];
    o += fmaxf(a, 0.f) * sw3[m];
  }
  out[g] = o;
}

// ==================================================================
// PATH B fallback kernels (two-pass CSR, f32; plain cnt semantics)
// ==================================================================
__global__ __launch_bounds__(256) void hist_kernel(
    const int* __restrict__ ei, int* __restrict__ cnt) {
  int t = blockIdx.x * blockDim.x + threadIdx.x;
  int e = t * 4;
  if (e >= NEDGES) return;
  int4 d4 = *(const int4*)(ei + NEDGES + e);
  atomicAdd(cnt + d4.x, 1);
  atomicAdd(cnt + d4.y, 1);
  atomicAdd(cnt + d4.z, 1);
  atomicAdd(cnt + d4.w, 1);
}

__global__ __launch_bounds__(256) void scan_bsum_kernel(
    const int* __restrict__ cnt, int* __restrict__ bsum) {
  __shared__ int s[256];
  int base = blockIdx.x * SCAN_CHUNK + threadIdx.x * 4;
  int t = 0;
#pragma unroll
  for (int k = 0; k < 4; k++) {
    int i = base + k;
    if (i < NNODES) t += cnt[i];
  }
  s[threadIdx.x] = t;
  __syncthreads();
  for (int off = 128; off; off >>= 1) {
    if (threadIdx.x < off) s[threadIdx.x] += s[threadIdx.x + off];
    __syncthreads();
  }
  if (threadIdx.x == 0) bsum[blockIdx.x] = s[0];
}

__global__ void scan_bsum_excl_kernel(int* __restrict__ bsum) {
  if (threadIdx.x == 0 && blockIdx.x == 0) {
    int acc = 0;
    for (int b = 0; b < NSCAN_BLOCKS; b++) {
      int v = bsum[b];
      bsum[b] = acc;
      acc += v;
    }
  }
}

__global__ __launch_bounds__(256) void scan_final_kernel(
    const int* __restrict__ cnt, const int* __restrict__ bsum,
    int* __restrict__ row_ptr, int* __restrict__ cursor) {
  __shared__ int s[256];
  int base = blockIdx.x * SCAN_CHUNK + threadIdx.x * 4;
  int c[4];
  int tsum = 0;
#pragma unroll
  for (int k = 0; k < 4; k++) {
    int i = base + k;
    c[k] = (i < NNODES) ? cnt[i] : 0;
    tsum += c[k];
  }
  s[threadIdx.x] = tsum;
  __syncthreads();
  for (int off = 1; off < 256; off <<= 1) {
    int x = 0;
    if (threadIdx.x >= off) x = s[threadIdx.x - off];
    __syncthreads();
    s[threadIdx.x] += x;
    __syncthreads();
  }
  int running = bsum[blockIdx.x] + s[threadIdx.x] - tsum;
#pragma unroll
  for (int k = 0; k < 4; k++) {
    int i = base + k;
    if (i < NNODES) {
      row_ptr[i] = running;
      cursor[i] = running;
      running += c[k];
    }
  }
}

__global__ __launch_bounds__(256) void fill_kernel(
    const int* __restrict__ ei, int* __restrict__ cursor,
    int* __restrict__ sorted_src) {
  int t = blockIdx.x * blockDim.x + threadIdx.x;
  int e = t * 4;
  if (e >= NEDGES) return;
  int4 s4 = *(const int4*)(ei + e);
  int4 d4 = *(const int4*)(ei + NEDGES + e);
  int p0 = atomicAdd(cursor + d4.x, 1);
  int p1 = atomicAdd(cursor + d4.y, 1);
  int p2 = atomicAdd(cursor + d4.z, 1);
  int p3 = atomicAdd(cursor + d4.w, 1);
  sorted_src[p0] = s4.x;
  sorted_src[p1] = s4.y;
  sorted_src[p2] = s4.z;
  sorted_src[p3] = s4.w;
}

__global__ __launch_bounds__(256) void agg0f_kernel(
    const float* __restrict__ x, const int* __restrict__ slots,
    const int* __restrict__ row_ptr, const int* __restrict__ cnt,
    float* __restrict__ agg) {
  int tid = blockIdx.x * blockDim.x + threadIdx.x;
  int node = tid / 3;
  int q = tid - node * 3;
  if (node >= NNODES) return;
  int start = row_ptr[node];
  int deg = cnt[node];
  float4 a0 = {0,0,0,0};
  for (int n = 0; n < deg; n++)
    f4add(a0, *(const float4*)(x + (size_t)slots[start + n] * INDIM + q * 4));
  float inv = 1.0f / fmaxf((float)deg, 1.0f);
  float4 r; r.x = a0.x * inv; r.y = a0.y * inv; r.z = a0.z * inv; r.w = a0.w * inv;
  *(float4*)(agg + (size_t)node * INDIM + q * 4) = r;
}

__global__ __launch_bounds__(256) void agg1f_kernel(
    const float* __restrict__ h0, const int* __restrict__ slots,
    const int* __restrict__ row_ptr, const int* __restrict__ cnt,
    float* __restrict__ agg) {
  int tid = blockIdx.x * blockDim.x + threadIdx.x;
  int node = tid / 12;
  int q = tid - node * 12;
  if (node >= NNODES) return;
  int start = row_ptr[node];
  int deg = cnt[node];
  float4 a0 = {0,0,0,0};
  for (int n = 0; n < deg; n++)
    f4add(a0, *(const float4*)(h0 + (size_t)slots[start + n] * HID + q * 4));
  float inv = 1.0f / fmaxf((float)deg, 1.0f);
  float4 r; r.x = a0.x * inv; r.y = a0.y * inv; r.z = a0.z * inv; r.w = a0.w * inv;
  *(float4*)(agg + (size_t)node * HID + q * 4) = r;
}

__global__ __launch_bounds__(256) void sage0_kernel(
    const float* __restrict__ x, const float* __restrict__ agg,
    const float* __restrict__ wl, const float* __restrict__ wr,
    const float* __restrict__ bc,
    float* __restrict__ hpre, float* __restrict__ stats) {
  __shared__ float swl[HID * INDIM], swr[HID * INDIM], sbc[HID];
  __shared__ float ssum[HID], ssq[HID];
  for (int t = threadIdx.x; t < HID * INDIM; t += blockDim.x) { swl[t] = wl[t]; swr[t] = wr[t]; }
  if (threadIdx.x < HID) { sbc[threadIdx.x] = bc[threadIdx.x]; ssum[threadIdx.x] = 0.f; ssq[threadIdx.x] = 0.f; }
  __syncthreads();
  int i = blockIdx.x * blockDim.x + threadIdx.x;
  bool valid = (i < NNODES);
  float xi[INDIM], ag[INDIM];
  if (valid) {
    const float4* xp = (const float4*)(x + (size_t)i * INDIM);
    const float4* mp = (const float4*)(agg + (size_t)i * INDIM);
#pragma unroll
    for (int q = 0; q < 3; q++) {
      float4 v = xp[q];
      xi[q * 4 + 0] = v.x; xi[q * 4 + 1] = v.y; xi[q * 4 + 2] = v.z; xi[q * 4 + 3] = v.w;
      float4 m = mp[q];
      ag[q * 4 + 0] = m.x; ag[q * 4 + 1] = m.y; ag[q * 4 + 2] = m.z; ag[q * 4 + 3] = m.w;
    }
  } else {
#pragma unroll
    for (int j = 0; j < INDIM; j++) { xi[j] = 0.f; ag[j] = 0.f; }
  }
  int lane = threadIdx.x & 63;
  for (int kb = 0; kb < HID; kb += 4) {
    float o[4];
#pragma unroll
    for (int t = 0; t < 4; t++) {
      int k = kb + t;
      float acc = valid ? sbc[k] : 0.f;
#pragma unroll
      for (int j = 0; j < INDIM; j++)
        acc += ag[j] * swl[k * INDIM + j] + xi[j] * swr[k * INDIM + j];
      o[t] = acc;
    }
    if (valid) {
      float4 v; v.x = o[0]; v.y = o[1]; v.z = o[2]; v.w = o[3];
      *((float4*)(hpre + (size_t)i * HID + kb)) = v;
    }
#pragma unroll
    for (int t = 0; t < 4; t++) {
      float s = o[t], q = o[t] * o[t];
#pragma unroll
      for (int off = 32; off; off >>= 1) { s += __shfl_xor(s, off); q += __shfl_xor(q, off); }
      if (lane == 0) { atomicAdd(&ssum[kb + t], s); atomicAdd(&ssq[kb + t], q); }
    }
  }
  __syncthreads();
  if (threadIdx.x < HID) {
    atomicAdd(&stats[threadIdx.x], ssum[threadIdx.x]);
    atomicAdd(&stats[HID + threadIdx.x], ssq[threadIdx.x]);
  }
}

__global__ __launch_bounds__(256) void bn_relu_kernel(
    float* __restrict__ h, const float* __restrict__ stats,
    const float* __restrict__ g, const float* __restrict__ be) {
  __shared__ float sc[HID], sh[HID];
  if (threadIdx.x < HID) {
    int k = threadIdx.x;
    float m = stats[k] * (1.0f / NNODES);
    float v = stats[HID + k] * (1.0f / NNODES) - m * m;
    float s = g[k] * rsqrtf(v + CEPS);
    sc[k] = s; sh[k] = be[k] - m * s;
  }
  __syncthreads();
  const int total = NNODES * (HID / 4);
  int stride = gridDim.x * blockDim.x;
  for (int idx = blockIdx.x * blockDim.x + threadIdx.x; idx < total; idx += stride) {
    int kb = (idx % (HID / 4)) * 4;
    float4 v = ((float4*)h)[idx];
    v.x = fmaxf(v.x * sc[kb + 0] + sh[kb + 0], 0.f);
    v.y = fmaxf(v.y * sc[kb + 1] + sh[kb + 1], 0.f);
    v.z = fmaxf(v.z * sc[kb + 2] + sh[kb + 2], 0.f);
    v.w = fmaxf(v.w * sc[kb + 3] + sh[kb + 3], 0.f);
    ((float4*)h)[idx] = v;
  }
}

__global__ __launch_bounds__(256) void sage1_kernel(
    const float* __restrict__ h0, float* __restrict__ agg_hpre,
    const float* __restrict__ wl, const float* __restrict__ wr,
    const float* __restrict__ bc, float* __restrict__ stats) {
  __shared__ float swl[HID * HID], swr[HID * HID], sbc[HID];
  __shared__ float ssum[HID], ssq[HID];
  for (int t = threadIdx.x; t < HID * HID; t += blockDim.x) { swl[t] = wl[t]; swr[t] = wr[t]; }
  if (threadIdx.x < HID) { sbc[threadIdx.x] = bc[threadIdx.x]; ssum[threadIdx.x] = 0.f; ssq[threadIdx.x] = 0.f; }
  __syncthreads();
  int i = blockIdx.x * blockDim.x + threadIdx.x;
  bool valid = (i < NNODES);
  float ag[HID], hx[HID];
  if (valid) {
    const float4* mp = (const float4*)(agg_hpre + (size_t)i * HID);
    const float4* hp = (const float4*)(h0 + (size_t)i * HID);
#pragma unroll
    for (int q = 0; q < HID / 4; q++) {
      float4 m = mp[q];
      ag[q * 4 + 0] = m.x; ag[q * 4 + 1] = m.y; ag[q * 4 + 2] = m.z; ag[q * 4 + 3] = m.w;
      float4 v = hp[q];
      hx[q * 4 + 0] = v.x; hx[q * 4 + 1] = v.y; hx[q * 4 + 2] = v.z; hx[q * 4 + 3] = v.w;
    }
  } else {
#pragma unroll
    for (int j = 0; j < HID; j++) { ag[j] = 0.f; hx[j] = 0.f; }
  }
  int lane = threadIdx.x & 63;
  for (int kb = 0; kb < HID; kb += 4) {
    float o[4];
#pragma unroll
    for (int t = 0; t < 4; t++) {
      int k = kb + t;
      float acc = valid ? sbc[k] : 0.f;
#pragma unroll
      for (int j = 0; j < HID; j++)
        acc += ag[j] * swl[k * HID + j] + hx[j] * swr[k * HID + j];
      o[t] = acc;
    }
    if (valid) {
      float4 v; v.x = o[0]; v.y = o[1]; v.z = o[2]; v.w = o[3];
      *((float4*)(agg_hpre + (size_t)i * HID + kb)) = v;
    }
#pragma unroll
    for (int t = 0; t < 4; t++) {
      float s = o[t], q = o[t] * o[t];
#pragma unroll
      for (int off = 32; off; off >>= 1) { s += __shfl_xor(s, off); q += __shfl_xor(q, off); }
      if (lane == 0) { atomicAdd(&ssum[kb + t], s); atomicAdd(&ssq[kb + t], q); }
    }
  }
  __syncthreads();
  if (threadIdx.x < HID) {
    atomicAdd(&stats[threadIdx.x], ssum[threadIdx.x]);
    atomicAdd(&stats[HID + threadIdx.x], ssq[threadIdx.x]);
  }
}

__global__ __launch_bounds__(64) void bn_pool1w_kernel(
    const float* __restrict__ hpre, const float* __restrict__ stats,
    const float* __restrict__ g, const float* __restrict__ be,
    const int* __restrict__ gstart,
    float* __restrict__ meanp, float* __restrict__ maxp) {
  int gr = blockIdx.x;
  int f = threadIdx.x;
  if (f >= HID) return;
  float m = stats[f] * (1.0f / NNODES);
  float v = stats[HID + f] * (1.0f / NNODES) - m * m;
  float sc = g[f] * rsqrtf(v + CEPS);
  float sh = be[f] - m * sc;
  int start = gstart[gr], end = gstart[gr + 1];
  float sum = 0.f, mx = 0.f;
  for (int i = start; i < end; i++) {
    float val = fmaxf(hpre[(size_t)i * HID + f] * sc + sh, 0.f);
    sum += val;
    mx = fmaxf(mx, val);
  }
  float n = (float)(end - start);
  meanp[(size_t)gr * HID + f] = sum / fmaxf(n, 1.0f);
  maxp[(size_t)gr * HID + f] = mx;
}

// ------------------------------------------------------------------
extern "C" void kernel_launch(void* const* d_in, const int* in_sizes, int n_in,
                              void* d_out, int out_size, void* d_ws, size_t ws_size,
                              hipStream_t stream) {
  (void)in_sizes; (void)n_in; (void)out_size;
  const float* x     = (const float*)d_in[0];
  const int*   ei    = (const int*)d_in[1];
  const int*   batch = (const int*)d_in[2];
  const float* adme  = (const float*)d_in[3];
  const float* wl0 = (const float*)d_in[4];
  const float* wr0 = (const float*)d_in[5];
  const float* bc0 = (const float*)d_in[6];
  const float* g0  = (const float*)d_in[7];
  const float* be0 = (const float*)d_in[8];
  const float* wl1 = (const float*)d_in[9];
  const float* wr1 = (const float*)d_in[10];
  const float* bc1 = (const float*)d_in[11];
  const float* g1  = (const float*)d_in[12];
  const float* be1 = (const float*)d_in[13];
  const float* hw1 = (const float*)d_in[14];
  const float* hb1 = (const float*)d_in[15];
  const float* hg1 = (const float*)d_in[16];
  const float* hbe1= (const float*)d_in[17];
  const float* hw2 = (const float*)d_in[18];
  const float* hb2 = (const float*)d_in[19];
  const float* hw3 = (const float*)d_in[20];
  const float* hb3 = (const float*)d_in[21];
  float* out = (float*)d_out;

  size_t elems_A = (size_t)NNODES * HID * 2 + (size_t)NNODES * CAP + 2048
                 + 512 + NNODES + 4 * HID
                 + (size_t)NGRAPHS * HID * 2 + (size_t)NGRAPHS * 64 + 128;
  bool padded = ws_size >= elems_A * 4 + 256;

  if (padded) {
    float* buf1 = (float*)d_ws;                            // [4.8M f32]
    float* buf2 = buf1 + (size_t)NNODES * HID;             // [4.8M f32]
    int* slots  = (int*)(buf2 + (size_t)NNODES * HID);     // [NNODES*CAP]
    int* gstart = slots + (size_t)NNODES * CAP;            // [2048]
    int* bucket_cursor = gstart + 2048;                    // [512]
    int* cnt    = bucket_cursor + 512;                     // [NNODES] tot|b1<<8|b2<<16|b3<<24
    float* stats0 = (float*)(cnt + NNODES);                // [2*HID]
    float* stats1 = stats0 + 2 * HID;                      // [2*HID]
    float* meanp = stats1 + 2 * HID;                       // [NGRAPHS*HID]
    float* maxp  = meanp + (size_t)NGRAPHS * HID;          // [NGRAPHS*HID]
    float* z1  = maxp + (size_t)NGRAPHS * HID;             // [NGRAPHS*64]
    float* hsc = z1 + (size_t)NGRAPHS * 64;                // [64]
    float* hsh = hsc + 64;                                 // [64]

    // overlays (timeline-disjoint):
    unsigned int* bucketed = (unsigned int*)buf2;          // live: p1 -> p2
    uint4* h0b = (uint4*)buf1;                             // bf16 h0: bn_relu_b16 -> sage1
    uint2* xb  = (uint2*)(buf1 + 4200000);                 // bf16 x: convert -> agg0

    hipMemsetAsync(bucket_cursor, 0, 512 * sizeof(int), stream);
    hipMemsetAsync(stats0, 0, 4 * HID * sizeof(float), stream);

    convert_x_kernel<<<(NNODES * INDIM / 8 + 255) / 256, 256, 0, stream>>>(x, (uint4*)xb);
    bucket_p1_kernel<<<P1_BLOCKS, P1_THREADS, 0, stream>>>(ei, bucket_cursor, bucketed);
    fill_p2_kernel<<<NBUCKET, 256, 0, stream>>>(bucketed, bucket_cursor, slots, cnt);
    graph_start_kernel<<<(NGRAPHS + 1 + 63) / 64, 64, 0, stream>>>(batch, gstart);

    // layer 0
    agg0_b_kernel<<<(NNODES * 3 + 255) / 256, 256, 0, stream>>>(xb, slots, cnt, buf1);
    sage0_4k_kernel<<<(NNODES * 4 + 255) / 256, 256, 0, stream>>>(x, buf1, wl0, wr0, bc0, buf2, stats0);
    bn_relu_b16_kernel<<<(NNODES * 6 + 255) / 256, 256, 0, stream>>>(buf2, stats0, g0, be0, h0b);

    // layer 1
    agg1_b_kernel<<<(NNODES * 6 + 255) / 256, 256, 0, stream>>>(h0b, slots, cnt, buf2);
    sage1_2n_kernel<<<(NNODES * 2 + 255) / 256, 256, 0, stream>>>(buf2, (const uint2*)h0b, wl1, wr1, bc1, buf2, stats1);
    bn_pool_kernel<<<NGRAPHS, 256, 0, stream>>>(buf2, stats1, g1, be1, gstart, meanp, maxp);

    // head
    head1_kernel<<<NGRAPHS, 64, 0, stream>>>(meanp, maxp, adme, hw1, hb1, z1);
    headstats_kernel<<<64, 256, 0, stream>>>(z1, hg1, hbe1, hsc, hsh);
    head2_kernel<<<(NGRAPHS + 255) / 256, 256, 0, stream>>>(z1, hsc, hsh, hw2, hb2, hw3, hb3, out);
  } else {
    // ----- Path B: two-pass CSR fallback (f32 end-to-end) -----
    float* buf1 = (float*)d_ws;
    float* buf2 = buf1 + (size_t)NNODES * HID;
    int* sorted_src = (int*)(buf2 + (size_t)NNODES * HID);
    int* row_ptr = sorted_src + NEDGES;
    int* cursor  = row_ptr + NNODES;
    int* bsum    = cursor + NNODES;
    int* gstart  = bsum + 128;
    int* cnt   = gstart + 2048;
    float* stats0 = (float*)(cnt + NNODES);
    float* stats1 = stats0 + 2 * HID;
    float* meanp = stats1 + 2 * HID;
    float* maxp  = meanp + (size_t)NGRAPHS * HID;
    float* z1  = maxp + (size_t)NGRAPHS * HID;
    float* hsc = z1 + (size_t)NGRAPHS * 64;
    float* hsh = hsc + 64;

    size_t zero_bytes = (char*)(stats1 + 2 * HID) - (char*)cnt;
    hipMemsetAsync(cnt, 0, zero_bytes, stream);

    hist_kernel<<<(NEDGES / 4 + 255) / 256, 256, 0, stream>>>(ei, cnt);
    scan_bsum_kernel<<<NSCAN_BLOCKS, 256, 0, stream>>>(cnt, bsum);
    scan_bsum_excl_kernel<<<1, 64, 0, stream>>>(bsum);
    scan_final_kernel<<<NSCAN_BLOCKS, 256, 0, stream>>>(cnt, bsum, row_ptr, cursor);
    fill_kernel<<<(NEDGES / 4 + 255) / 256, 256, 0, stream>>>(ei, cursor, sorted_src);
    graph_start_kernel<<<(NGRAPHS + 1 + 63) / 64, 64, 0, stream>>>(batch, gstart);

    agg0f_kernel<<<(NNODES * 3 + 255) / 256, 256, 0, stream>>>(x, sorted_src, row_ptr, cnt, buf1);
    sage0_kernel<<<(NNODES + 255) / 256, 256, 0, stream>>>(x, buf1, wl0, wr0, bc0, buf2, stats0);
    bn_relu_kernel<<<2048, 256, 0, stream>>>(buf2, stats0, g0, be0);

    agg1f_kernel<<<(NNODES * 12 + 255) / 256, 256, 0, stream>>>(buf2, sorted_src, row_ptr, cnt, buf1);
    sage1_kernel<<<(NNODES + 255) / 256, 256, 0, stream>>>(buf2, buf1, wl1, wr1, bc1, stats1);
    bn_pool1w_kernel<<<NGRAPHS, 64, 0, stream>>>(buf1, stats1, g1, be1, gstart, meanp, maxp);

    head1_kernel<<<NGRAPHS, 64, 0, stream>>>(meanp, maxp, adme, hw1, hb1, z1);
    headstats_kernel<<<64, 256, 0, stream>>>(z1, hg1, hbe1, hsc, hsh);
    head2_kernel<<<(NGRAPHS + 255) / 256, 256, 0, stream>>>(z1, hsc, hsh, hw2, hb2, hw3, hb3, out);
  }
}